// Round 1
// baseline (688.295 us; speedup 1.0000x reference)
//
#include <hip/hip_runtime.h>

// ---------------- common helpers ----------------
typedef __attribute__((ext_vector_type(8))) short short8;
typedef __attribute__((ext_vector_type(4))) float f32x4;

__device__ __forceinline__ unsigned short f2b(float f) {
    union { float f; unsigned u; } uf; uf.f = f;
    unsigned r = uf.u + 0x7fffu + ((uf.u >> 16) & 1u);   // RNE, finite inputs
    return (unsigned short)(r >> 16);
}
__device__ __forceinline__ float b2f(unsigned short b) {
    union { unsigned u; float f; } uf; uf.u = ((unsigned)b) << 16;
    return uf.f;
}
__device__ __forceinline__ void gload_lds16(const void* g, void* l) {
    __builtin_amdgcn_global_load_lds(
        (const __attribute__((address_space(1))) void*)g,
        (__attribute__((address_space(3))) void*)l,
        16, 0, 0);
}

#define B_SZ 4096
#define F_ST 20
#define F_DY 10
#define MLEN 50
#define E_SZ 16
#define F_ALL 30
#define NPAIR 435
#define DIN 6960
#define KP1 6976          /* DIN padded to 32 */
#define H_SZ 512
#define BN_EPS 1e-5f

// ---------------- pair table ----------------
__global__ void k_pairs(int* pi, int* pj) {
    int t = threadIdx.x;
    for (int p = t; p < NPAIR; p += 64) {
        int i = 0, rem = p;
        while (rem >= (F_ALL - 1) - i) { rem -= (F_ALL - 1) - i; ++i; }
        pi[p] = i; pj[p] = i + 1 + rem;
    }
}

// ---------------- embeddings + linear terms ----------------
__global__ __launch_bounds__(512) void k_embed(
    const int* __restrict__ st_ids, const int* __restrict__ dy_ids,
    const int* __restrict__ dy_len, const float* __restrict__ st_emb,
    const float* __restrict__ dy_emb, const float* __restrict__ st_lr,
    const float* __restrict__ dy_lr, const float* __restrict__ bias,
    float* __restrict__ all_emb, float* __restrict__ lr_score)
{
    int b = blockIdx.x, t = threadIdx.x;
    __shared__ float red[32];
    if (t < 320) {                       // static embeddings: 20 fields x 16
        int f = t >> 4, e = t & 15;
        int id = st_ids[b * F_ST + f];
        all_emb[((long)b * F_ALL + f) * E_SZ + e] = st_emb[(long)id * E_SZ + e];
    } else if (t < 480) {                // dynamic masked-mean: 10 fields x 16
        int tt = t - 320, f = tt >> 4, e = tt & 15;
        int len = dy_len[b * F_DY + f]; if (len < 1) len = 1;
        const int* ids = dy_ids + ((long)b * F_DY + f) * MLEN;
        float s = 0.f;
        for (int m = 0; m < len; ++m) s += dy_emb[(long)ids[m] * E_SZ + e];
        all_emb[((long)b * F_ALL + F_ST + f) * E_SZ + e] = s / (float)len;
    } else if (t < 500) {                // static lr
        int f = t - 480;
        red[f] = st_lr[st_ids[b * F_ST + f]];
    } else if (t < 510) {                // dynamic lr (sum)
        int f = t - 500;
        int len = dy_len[b * F_DY + f]; if (len < 1) len = 1;
        const int* ids = dy_ids + ((long)b * F_DY + f) * MLEN;
        float s = 0.f;
        for (int m = 0; m < len; ++m) s += dy_lr[ids[m]];
        red[F_ST + f] = s;
    }
    __syncthreads();
    if (t == 0) {
        float s = bias[0];
        for (int i = 0; i < F_ALL; ++i) s += red[i];
        lr_score[b] = s;
    }
}

// ---------------- pairwise products -> x (bf16) + BN1 stats ----------------
__global__ __launch_bounds__(256) void k_x(
    const float* __restrict__ all_emb, const int* __restrict__ pi,
    const int* __restrict__ pj, unsigned short* __restrict__ x16,
    float* __restrict__ s1, float* __restrict__ s1q)
{
    __shared__ float es[16 * 480];
    int t = threadIdx.x, b0 = blockIdx.x * 16;
    for (int idx = t; idx < 16 * 480; idx += 256)
        es[idx] = all_emb[(long)b0 * 480 + idx];

    int ci[28], cj[28];
#pragma unroll
    for (int k = 0; k < 28; ++k) {
        int d = t + (k << 8);
        if (d < DIN) {
            int p = d >> 4, e = d & 15;
            ci[k] = pi[p] * E_SZ + e;
            cj[k] = pj[p] * E_SZ + e;
        } else { ci[k] = -1; cj[k] = 0; }
    }
    float sum[28], sq[28];
#pragma unroll
    for (int k = 0; k < 28; ++k) { sum[k] = 0.f; sq[k] = 0.f; }
    __syncthreads();

    for (int r = 0; r < 16; ++r) {
        const float* row = &es[r * 480];
        long ob = (long)(b0 + r) * KP1;
#pragma unroll
        for (int k = 0; k < 28; ++k) {
            int d = t + (k << 8);
            if (ci[k] >= 0) {
                float v = row[ci[k]] * row[cj[k]];
                unsigned short h = f2b(v);
                x16[ob + d] = h;
                float vb = b2f(h);
                sum[k] += vb; sq[k] += vb * vb;
            } else if (d < KP1) {
                x16[ob + d] = 0;          // K padding
            }
        }
    }
#pragma unroll
    for (int k = 0; k < 28; ++k) {
        int d = t + (k << 8);
        if (ci[k] >= 0) { atomicAdd(&s1[d], sum[k]); atomicAdd(&s1q[d], sq[k]); }
    }
}

// ---------------- BN fold: a = g*rsqrt(var+eps), c = b - mean*a ----------------
__global__ void k_fold(const float* __restrict__ s, const float* __restrict__ sqs,
                       const float* __restrict__ g, const float* __restrict__ bb,
                       float* __restrict__ a, float* __restrict__ c, int n)
{
    int d = blockIdx.x * 256 + threadIdx.x;
    if (d < n) {
        float m = s[d] * (1.f / 4096.f);
        float var = sqs[d] * (1.f / 4096.f) - m * m;
        float av = g[d] * rsqrtf(var + BN_EPS);
        a[d] = av; c[d] = bb[d] - m * av;
    }
}

// ---------------- const1[j] = sum_d c1[d]*W1[d,j] ----------------
__global__ __launch_bounds__(256) void k_const1(
    const float* __restrict__ W1, const float* __restrict__ c1,
    float* __restrict__ con)
{
    int t = threadIdx.x;
    int d0 = blockIdx.x * 218;
    int d1 = d0 + 218; if (d1 > DIN) d1 = DIN;
    float a0 = 0.f, a1v = 0.f;
    for (int d = d0; d < d1; ++d) {
        float c = c1[d];
        a0  += c * W1[(long)d * H_SZ + t];
        a1v += c * W1[(long)d * H_SZ + t + 256];
    }
    atomicAdd(&con[t], a0);
    atomicAdd(&con[t + 256], a1v);
}

// ---------------- W1^T cast: w1t[n][k] = a1[k]*W1[k][n], bf16, K padded ----------------
__global__ __launch_bounds__(256) void k_w1t(
    const float* __restrict__ W1, const float* __restrict__ a1,
    unsigned short* __restrict__ w1t)
{
    int gi = blockIdx.x * 256 + threadIdx.x;   // 872*512 groups
    int kg = gi >> 9, n = gi & 511;
    short8 out;
#pragma unroll
    for (int i = 0; i < 8; ++i) {
        int k = kg * 8 + i;
        float v = (k < DIN) ? a1[k] * W1[(long)k * H_SZ + n] : 0.f;
        out[i] = (short)f2b(v);
    }
    *(short8*)(w1t + (long)n * KP1 + kg * 8) = out;
}

// ---------------- W2^T cast + const2 ----------------
__global__ __launch_bounds__(256) void k_w2t(
    const float* __restrict__ W2, const float* __restrict__ a2,
    const float* __restrict__ c2, unsigned short* __restrict__ w2t,
    float* __restrict__ con)
{
    int gi = blockIdx.x * 256 + threadIdx.x;   // 64*512 groups
    int kg = gi >> 9, n = gi & 511;
    short8 out; float cacc = 0.f;
#pragma unroll
    for (int i = 0; i < 8; ++i) {
        int k = kg * 8 + i;
        float w = W2[(long)k * H_SZ + n];
        out[i] = (short)f2b(a2[k] * w);
        cacc += c2[k] * w;
    }
    *(short8*)(w2t + (long)n * H_SZ + kg * 8) = out;
    atomicAdd(&con[n], cacc);
}

// ---------------- bf16 MFMA GEMM: Out = relu(A @ Bt^T + cvec + bvec), bf16 out ----
// A: [M, Kp] bf16 row-major.  Bt: [N, Kp] bf16 row-major (B transposed).
// block tile 128(M) x 64(N); 512 threads = 8 waves as 4x2 of 32x32 wave tiles.
__global__ __launch_bounds__(512) void k_gemm(
    const unsigned short* __restrict__ A, const unsigned short* __restrict__ Bt,
    const float* __restrict__ cvec, const float* __restrict__ bvec,
    unsigned short* __restrict__ Out, int Kp)
{
    __shared__ __align__(16) short As[128 * 32];
    __shared__ __align__(16) short Bs[64 * 32];
    const int t = threadIdx.x;
    const int w = t >> 6, l = t & 63;
    const int wm = w >> 1, wn = w & 1;
    const int lm = l & 15, lq = l >> 4;
    const int row0 = blockIdx.y * 128;
    const int col0 = blockIdx.x * 64;

    const unsigned short* gA = A + (long)(row0 + (t >> 2)) * Kp + ((t & 3) * 8);
    const unsigned short* gB = Bt + (long)(col0 + ((t >> 2) & 63)) * Kp + ((t & 3) * 8);
    short* AsW = As + w * 512;            // wave-uniform LDS dest (lane*16B appended by HW)
    short* BsW = Bs + w * 512;

    const short* aBase0 = As + (wm * 32 + lm) * 32 + lq * 8;
    const short* aBase1 = aBase0 + 16 * 32;
    const short* bBase0 = Bs + (wn * 32 + lm) * 32 + lq * 8;
    const short* bBase1 = bBase0 + 16 * 32;

    f32x4 acc00 = {0.f,0.f,0.f,0.f}, acc01 = acc00, acc10 = acc00, acc11 = acc00;

    const int ksteps = Kp >> 5;
    for (int kt = 0; kt < ksteps; ++kt) {
        gload_lds16(gA, AsW);             // 512 thr x 16B = 8KB A tile
        if (t < 256) gload_lds16(gB, BsW);// 256 thr x 16B = 4KB B tile
        __syncthreads();                  // drains vmcnt before barrier release
        short8 af0 = *(const short8*)aBase0;
        short8 af1 = *(const short8*)aBase1;
        short8 bf0 = *(const short8*)bBase0;
        short8 bf1 = *(const short8*)bBase1;
        acc00 = __builtin_amdgcn_mfma_f32_16x16x32_bf16(af0, bf0, acc00, 0, 0, 0);
        acc01 = __builtin_amdgcn_mfma_f32_16x16x32_bf16(af0, bf1, acc01, 0, 0, 0);
        acc10 = __builtin_amdgcn_mfma_f32_16x16x32_bf16(af1, bf0, acc10, 0, 0, 0);
        acc11 = __builtin_amdgcn_mfma_f32_16x16x32_bf16(af1, bf1, acc11, 0, 0, 0);
        __syncthreads();
        gA += 32; gB += 32;
    }

    // epilogue: C/D layout col=lane&15, row=(lane>>4)*4+reg
    f32x4 accs[2][2] = {{acc00, acc01}, {acc10, acc11}};
#pragma unroll
    for (int ni = 0; ni < 2; ++ni) {
        int col = col0 + wn * 32 + ni * 16 + lm;
        float cb = cvec[col] + bvec[col];
#pragma unroll
        for (int mi = 0; mi < 2; ++mi) {
            int rbase = row0 + wm * 32 + mi * 16 + lq * 4;
#pragma unroll
            for (int r = 0; r < 4; ++r) {
                float v = accs[mi][ni][r] + cb;
                v = v > 0.f ? v : 0.f;     // relu
                Out[(long)(rbase + r) * H_SZ + col] = f2b(v);
            }
        }
    }
}

// ---------------- column stats over 512-wide bf16 activations ----------------
__global__ __launch_bounds__(256) void k_colstats(
    const unsigned short* __restrict__ X, float* __restrict__ s,
    float* __restrict__ sq)
{
    int t = threadIdx.x, r0 = blockIdx.x * 256;
    float a0 = 0.f, a1v = 0.f, q0 = 0.f, q1 = 0.f;
    for (int r = 0; r < 256; ++r) {
        const unsigned short* row = X + (long)(r0 + r) * H_SZ;
        float v0 = b2f(row[t]), v1 = b2f(row[t + 256]);
        a0 += v0; q0 += v0 * v0; a1v += v1; q1 += v1 * v1;
    }
    atomicAdd(&s[t], a0);  atomicAdd(&sq[t], q0);
    atomicAdd(&s[t + 256], a1v); atomicAdd(&sq[t + 256], q1);
}

// ---------------- w3s[d] = sum_j W3[d][j] ----------------
__global__ __launch_bounds__(256) void k_w3s(const float* __restrict__ W3,
                                             float* __restrict__ w3s)
{
    int t = threadIdx.x;
    int row = blockIdx.x * 16 + (t >> 4), sub = t & 15;
    float acc = 0.f;
    for (int i = 0; i < 32; ++i) acc += W3[(long)row * H_SZ + sub + i * 16];
#pragma unroll
    for (int s = 8; s; s >>= 1) acc += __shfl_xor(acc, s, 16);
    if (sub == 0) w3s[row] = acc;
}

// ---------------- final: scores = lr + (a3*r2+c3)·w3s + sum(b3) ----------------
__global__ __launch_bounds__(256) void k_final(
    const unsigned short* __restrict__ r2, const float* __restrict__ a3,
    const float* __restrict__ c3, const float* __restrict__ w3s,
    const float* __restrict__ b3, const float* __restrict__ lr_score,
    float* __restrict__ out)
{
    int t = threadIdx.x, w = t >> 6, l = t & 63;
    int b = blockIdx.x * 4 + w;
    float acc = 0.f;
#pragma unroll
    for (int i = 0; i < 8; ++i) {
        int e = i * 64 + l;
        float v = a3[e] * b2f(r2[(long)b * H_SZ + e]) + c3[e];
        acc += v * w3s[e] + b3[e];
    }
    for (int s = 32; s; s >>= 1) acc += __shfl_down(acc, s, 64);
    if (l == 0) out[b] = lr_score[b] + acc;
}

// ---------------- launcher ----------------
extern "C" void kernel_launch(void* const* d_in, const int* in_sizes, int n_in,
                              void* d_out, int out_size, void* d_ws, size_t ws_size,
                              hipStream_t stream) {
    const int*   st_ids = (const int*)d_in[0];
    const int*   dy_ids = (const int*)d_in[1];
    const int*   dy_len = (const int*)d_in[2];
    const float* st_emb = (const float*)d_in[3];
    const float* dy_emb = (const float*)d_in[4];
    const float* st_lr  = (const float*)d_in[5];
    const float* dy_lr  = (const float*)d_in[6];
    const float* bias   = (const float*)d_in[7];
    const float* bn1_g  = (const float*)d_in[8];
    const float* bn1_b  = (const float*)d_in[9];
    const float* W1     = (const float*)d_in[10];
    const float* b1     = (const float*)d_in[11];
    const float* bn2_g  = (const float*)d_in[12];
    const float* bn2_b  = (const float*)d_in[13];
    const float* W2     = (const float*)d_in[14];
    const float* b2     = (const float*)d_in[15];
    const float* bn3_g  = (const float*)d_in[16];
    const float* bn3_b  = (const float*)d_in[17];
    const float* W3     = (const float*)d_in[18];
    const float* b3     = (const float*)d_in[19];
    // d_in[20..23] (bn_out_*, W_out, b_out) feed only the dead final layer — skipped.

    char* ws = (char*)d_ws;
    size_t off = 0;
    auto alloc = [&](size_t bytes) -> char* {
        char* p = ws + off;
        off = (off + bytes + 255) & ~(size_t)255;
        return p;
    };
    float*          all_emb = (float*)alloc((size_t)B_SZ * 480 * 4);
    unsigned short* x16     = (unsigned short*)alloc((size_t)B_SZ * KP1 * 2);
    unsigned short* w1t     = (unsigned short*)alloc((size_t)H_SZ * KP1 * 2);
    unsigned short* r1      = (unsigned short*)alloc((size_t)B_SZ * H_SZ * 2);
    unsigned short* w2t     = (unsigned short*)alloc((size_t)H_SZ * H_SZ * 2);
    unsigned short* r2      = (unsigned short*)alloc((size_t)B_SZ * H_SZ * 2);
    float*          lr_sc   = (float*)alloc(B_SZ * 4);
    char* zstart = ws + off;
    float* s1   = (float*)alloc(KP1 * 4);
    float* s1q  = (float*)alloc(KP1 * 4);
    float* con1 = (float*)alloc(H_SZ * 4);
    float* s2   = (float*)alloc(H_SZ * 4);
    float* s2q  = (float*)alloc(H_SZ * 4);
    float* con2 = (float*)alloc(H_SZ * 4);
    float* s3   = (float*)alloc(H_SZ * 4);
    float* s3q  = (float*)alloc(H_SZ * 4);
    size_t zbytes = (size_t)((ws + off) - zstart);
    float* a1 = (float*)alloc(KP1 * 4);
    float* c1 = (float*)alloc(KP1 * 4);
    float* a2 = (float*)alloc(H_SZ * 4);
    float* c2 = (float*)alloc(H_SZ * 4);
    float* a3 = (float*)alloc(H_SZ * 4);
    float* c3 = (float*)alloc(H_SZ * 4);
    float* w3s = (float*)alloc(H_SZ * 4);
    int* pi = (int*)alloc(NPAIR * 4);
    int* pj = (int*)alloc(NPAIR * 4);

    hipMemsetAsync(zstart, 0, zbytes, stream);
    k_pairs<<<1, 64, 0, stream>>>(pi, pj);
    k_embed<<<B_SZ, 512, 0, stream>>>(st_ids, dy_ids, dy_len, st_emb, dy_emb,
                                      st_lr, dy_lr, bias, all_emb, lr_sc);
    k_x<<<B_SZ / 16, 256, 0, stream>>>(all_emb, pi, pj, x16, s1, s1q);
    k_fold<<<28, 256, 0, stream>>>(s1, s1q, bn1_g, bn1_b, a1, c1, DIN);
    k_const1<<<32, 256, 0, stream>>>(W1, c1, con1);
    k_w1t<<<(872 * 512) / 256, 256, 0, stream>>>(W1, a1, w1t);
    k_gemm<<<dim3(8, 32), 512, 0, stream>>>(x16, w1t, con1, b1, r1, KP1);
    k_colstats<<<16, 256, 0, stream>>>(r1, s2, s2q);
    k_fold<<<2, 256, 0, stream>>>(s2, s2q, bn2_g, bn2_b, a2, c2, H_SZ);
    k_w2t<<<(64 * 512) / 256, 256, 0, stream>>>(W2, a2, c2, w2t, con2);
    k_gemm<<<dim3(8, 32), 512, 0, stream>>>(r1, w2t, con2, b2, r2, H_SZ);
    k_colstats<<<16, 256, 0, stream>>>(r2, s3, s3q);
    k_fold<<<2, 256, 0, stream>>>(s3, s3q, bn3_g, bn3_b, a3, c3, H_SZ);
    k_w3s<<<32, 256, 0, stream>>>(W3, w3s);
    k_final<<<B_SZ / 4, 256, 0, stream>>>(r2, a3, c3, w3s, b3, lr_sc, (float*)d_out);
}

// Round 2
// 438.828 us; speedup vs baseline: 1.5685x; 1.5685x over previous
//
#include <hip/hip_runtime.h>

// ---------------- common helpers ----------------
typedef __attribute__((ext_vector_type(8))) short short8;
typedef __attribute__((ext_vector_type(4))) float f32x4;

__device__ __forceinline__ unsigned short f2b(float f) {
    union { float f; unsigned u; } uf; uf.f = f;
    unsigned r = uf.u + 0x7fffu + ((uf.u >> 16) & 1u);   // RNE, finite inputs
    return (unsigned short)(r >> 16);
}
__device__ __forceinline__ float b2f(unsigned short b) {
    union { unsigned u; float f; } uf; uf.u = ((unsigned)b) << 16;
    return uf.f;
}
__device__ __forceinline__ void gload_lds16(const void* g, void* l) {
    __builtin_amdgcn_global_load_lds(
        (const __attribute__((address_space(1))) void*)g,
        (__attribute__((address_space(3))) void*)l,
        16, 0, 0);
}

#define B_SZ 4096
#define F_ST 20
#define F_DY 10
#define MLEN 50
#define E_SZ 16
#define F_ALL 30
#define NPAIR 435
#define DIN 6960
#define KP1 6976          /* DIN padded to 32 */
#define H_SZ 512
#define BN_EPS 1e-5f

// ---------------- pair table ----------------
__global__ void k_pairs(int* pi, int* pj) {
    int t = threadIdx.x;
    for (int p = t; p < NPAIR; p += 64) {
        int i = 0, rem = p;
        while (rem >= (F_ALL - 1) - i) { rem -= (F_ALL - 1) - i; ++i; }
        pi[p] = i; pj[p] = i + 1 + rem;
    }
}

// ---------------- static embedding gather (float4 per thread) ----------------
__global__ __launch_bounds__(256) void k_stemb(
    const int* __restrict__ st_ids, const float* __restrict__ st_emb,
    float* __restrict__ all_emb)
{
    int idx = blockIdx.x * 256 + threadIdx.x;    // (b*F_ST+f)*4 + e4
    int e4 = idx & 3, bf = idx >> 2;
    int b = bf / F_ST, f = bf % F_ST;
    int id = st_ids[bf];
    f32x4 v = *(const f32x4*)(st_emb + (long)id * E_SZ + e4 * 4);
    *(f32x4*)(all_emb + ((long)b * F_ALL + f) * E_SZ + e4 * 4) = v;
}

// ---------------- dynamic masked-mean: one wave per (b,f), lanes = 4m x 16e ----
__global__ __launch_bounds__(512) void k_dyemb(
    const int* __restrict__ dy_ids, const int* __restrict__ dy_len,
    const float* __restrict__ dy_emb, float* __restrict__ all_emb)
{
    int gw = blockIdx.x * 8 + (threadIdx.x >> 6);   // wave id = b*F_DY + f
    int l = threadIdx.x & 63;
    int b = gw / F_DY, f = gw - b * F_DY;
    int len = dy_len[b * F_DY + f]; if (len < 1) len = 1;
    const int* ids = dy_ids + ((long)b * F_DY + f) * MLEN;
    int e = l & 15, mq = l >> 4;
    float acc = 0.f;
    for (int m = mq; m < len; m += 4)
        acc += dy_emb[(long)ids[m] * E_SZ + e];
    acc += __shfl_xor(acc, 16, 64);
    acc += __shfl_xor(acc, 32, 64);
    if (l < 16)
        all_emb[((long)b * F_ALL + F_ST + f) * E_SZ + e] = acc / (float)len;
}

// ---------------- linear (lr) terms: one wave per batch row ----------------
__global__ __launch_bounds__(512) void k_lr(
    const int* __restrict__ st_ids, const int* __restrict__ dy_ids,
    const int* __restrict__ dy_len, const float* __restrict__ st_lr,
    const float* __restrict__ dy_lr, const float* __restrict__ bias,
    float* __restrict__ lr_score)
{
    int w = threadIdx.x >> 6, l = threadIdx.x & 63;
    int b = blockIdx.x * 8 + w;
    float acc = 0.f;
    if (l < F_ST) acc += st_lr[st_ids[b * F_ST + l]];
#pragma unroll
    for (int i = 0; i < 8; ++i) {                   // 10 fields x 50 slots = 500
        int idx = i * 64 + l;
        if (idx < F_DY * MLEN) {
            int f = idx / MLEN, m = idx - f * MLEN;
            int len = dy_len[b * F_DY + f]; if (len < 1) len = 1;
            if (m < len)
                acc += dy_lr[dy_ids[((long)b * F_DY + f) * MLEN + m]];
        }
    }
    for (int s = 32; s; s >>= 1) acc += __shfl_down(acc, s, 64);
    if (l == 0) lr_score[b] = bias[0] + acc;
}

// ---------------- pairwise products -> x (bf16) + BN1 stats ----------------
__global__ __launch_bounds__(256) void k_x(
    const float* __restrict__ all_emb, const int* __restrict__ pi,
    const int* __restrict__ pj, unsigned short* __restrict__ x16,
    float* __restrict__ s1, float* __restrict__ s1q)
{
    __shared__ float es[16 * 480];
    int t = threadIdx.x, b0 = blockIdx.x * 16;
    for (int idx = t; idx < 16 * 480; idx += 256)
        es[idx] = all_emb[(long)b0 * 480 + idx];

    int ci[28], cj[28];
#pragma unroll
    for (int k = 0; k < 28; ++k) {
        int d = t + (k << 8);
        if (d < DIN) {
            int p = d >> 4, e = d & 15;
            ci[k] = pi[p] * E_SZ + e;
            cj[k] = pj[p] * E_SZ + e;
        } else { ci[k] = -1; cj[k] = 0; }
    }
    float sum[28], sq[28];
#pragma unroll
    for (int k = 0; k < 28; ++k) { sum[k] = 0.f; sq[k] = 0.f; }
    __syncthreads();

    for (int r = 0; r < 16; ++r) {
        const float* row = &es[r * 480];
        long ob = (long)(b0 + r) * KP1;
#pragma unroll
        for (int k = 0; k < 28; ++k) {
            int d = t + (k << 8);
            if (ci[k] >= 0) {
                float v = row[ci[k]] * row[cj[k]];
                unsigned short h = f2b(v);
                x16[ob + d] = h;
                float vb = b2f(h);
                sum[k] += vb; sq[k] += vb * vb;
            } else if (d < KP1) {
                x16[ob + d] = 0;          // K padding
            }
        }
    }
#pragma unroll
    for (int k = 0; k < 28; ++k) {
        int d = t + (k << 8);
        if (ci[k] >= 0) { atomicAdd(&s1[d], sum[k]); atomicAdd(&s1q[d], sq[k]); }
    }
}

// ---------------- BN fold: a = g*rsqrt(var+eps), c = b - mean*a ----------------
__global__ void k_fold(const float* __restrict__ s, const float* __restrict__ sqs,
                       const float* __restrict__ g, const float* __restrict__ bb,
                       float* __restrict__ a, float* __restrict__ c, int n)
{
    int d = blockIdx.x * 256 + threadIdx.x;
    if (d < n) {
        float m = s[d] * (1.f / 4096.f);
        float var = sqs[d] * (1.f / 4096.f) - m * m;
        float av = g[d] * rsqrtf(var + BN_EPS);
        a[d] = av; c[d] = bb[d] - m * av;
    }
}

// ---------------- W1^T cast + const1 fold (w1t[n][k] = a1[k]*W1[k][n]) --------
__global__ __launch_bounds__(256) void k_w1t(
    const float* __restrict__ W1, const float* __restrict__ a1,
    const float* __restrict__ c1, unsigned short* __restrict__ w1t,
    float* __restrict__ con)
{
    int gi = blockIdx.x * 256 + threadIdx.x;   // 872*512 groups
    int kg = gi >> 9, n = gi & 511;
    short8 out; float cacc = 0.f;
#pragma unroll
    for (int i = 0; i < 8; ++i) {
        int k = kg * 8 + i;
        if (k < DIN) {
            float w = W1[(long)k * H_SZ + n];
            out[i] = (short)f2b(a1[k] * w);
            cacc += c1[k] * w;
        } else out[i] = 0;
    }
    *(short8*)(w1t + (long)n * KP1 + kg * 8) = out;
    atomicAdd(&con[n], cacc);
}

// ---------------- W2^T cast + const2 ----------------
__global__ __launch_bounds__(256) void k_w2t(
    const float* __restrict__ W2, const float* __restrict__ a2,
    const float* __restrict__ c2, unsigned short* __restrict__ w2t,
    float* __restrict__ con)
{
    int gi = blockIdx.x * 256 + threadIdx.x;   // 64*512 groups
    int kg = gi >> 9, n = gi & 511;
    short8 out; float cacc = 0.f;
#pragma unroll
    for (int i = 0; i < 8; ++i) {
        int k = kg * 8 + i;
        float w = W2[(long)k * H_SZ + n];
        out[i] = (short)f2b(a2[k] * w);
        cacc += c2[k] * w;
    }
    *(short8*)(w2t + (long)n * H_SZ + kg * 8) = out;
    atomicAdd(&con[n], cacc);
}

// ---------------- bf16 MFMA GEMM with fused relu + column stats ----------------
// Out = relu(A @ Bt^T + cvec + bvec) in bf16; atomically accumulates per-column
// sum / sum-of-squares of the quantized outputs into ss / sq.
__global__ __launch_bounds__(512) void k_gemm(
    const unsigned short* __restrict__ A, const unsigned short* __restrict__ Bt,
    const float* __restrict__ cvec, const float* __restrict__ bvec,
    unsigned short* __restrict__ Out, float* __restrict__ ss,
    float* __restrict__ sq, int Kp)
{
    __shared__ __align__(16) short As[128 * 32];
    __shared__ __align__(16) short Bs[64 * 32];
    const int t = threadIdx.x;
    const int w = t >> 6, l = t & 63;
    const int wm = w >> 1, wn = w & 1;
    const int lm = l & 15, lq = l >> 4;
    const int row0 = blockIdx.y * 128;
    const int col0 = blockIdx.x * 64;

    const unsigned short* gA = A + (long)(row0 + (t >> 2)) * Kp + ((t & 3) * 8);
    const unsigned short* gB = Bt + (long)(col0 + ((t >> 2) & 63)) * Kp + ((t & 3) * 8);
    short* AsW = As + w * 512;            // wave-uniform LDS dest
    short* BsW = Bs + w * 512;

    const short* aBase0 = As + (wm * 32 + lm) * 32 + lq * 8;
    const short* aBase1 = aBase0 + 16 * 32;
    const short* bBase0 = Bs + (wn * 32 + lm) * 32 + lq * 8;
    const short* bBase1 = bBase0 + 16 * 32;

    f32x4 acc00 = {0.f,0.f,0.f,0.f}, acc01 = acc00, acc10 = acc00, acc11 = acc00;

    const int ksteps = Kp >> 5;
    for (int kt = 0; kt < ksteps; ++kt) {
        gload_lds16(gA, AsW);
        if (t < 256) gload_lds16(gB, BsW);
        __syncthreads();
        short8 af0 = *(const short8*)aBase0;
        short8 af1 = *(const short8*)aBase1;
        short8 bf0 = *(const short8*)bBase0;
        short8 bf1 = *(const short8*)bBase1;
        acc00 = __builtin_amdgcn_mfma_f32_16x16x32_bf16(af0, bf0, acc00, 0, 0, 0);
        acc01 = __builtin_amdgcn_mfma_f32_16x16x32_bf16(af0, bf1, acc01, 0, 0, 0);
        acc10 = __builtin_amdgcn_mfma_f32_16x16x32_bf16(af1, bf0, acc10, 0, 0, 0);
        acc11 = __builtin_amdgcn_mfma_f32_16x16x32_bf16(af1, bf1, acc11, 0, 0, 0);
        __syncthreads();
        gA += 32; gB += 32;
    }

    // epilogue: C/D layout col=lane&15, row=(lane>>4)*4+reg
    f32x4 accs[2][2] = {{acc00, acc01}, {acc10, acc11}};
#pragma unroll
    for (int ni = 0; ni < 2; ++ni) {
        int col = col0 + wn * 32 + ni * 16 + lm;
        float cb = cvec[col] + bvec[col];
        float psum = 0.f, psq = 0.f;
#pragma unroll
        for (int mi = 0; mi < 2; ++mi) {
            int rbase = row0 + wm * 32 + mi * 16 + lq * 4;
#pragma unroll
            for (int r = 0; r < 4; ++r) {
                float v = accs[mi][ni][r] + cb;
                v = v > 0.f ? v : 0.f;     // relu
                unsigned short h = f2b(v);
                Out[(long)(rbase + r) * H_SZ + col] = h;
                float vb = b2f(h);
                psum += vb; psq += vb * vb;
            }
        }
        // reduce over lq (4 lanes share a column) then one atomic per column/wave
        psum += __shfl_xor(psum, 16, 64); psum += __shfl_xor(psum, 32, 64);
        psq  += __shfl_xor(psq , 16, 64); psq  += __shfl_xor(psq , 32, 64);
        if (lq == 0) { atomicAdd(&ss[col], psum); atomicAdd(&sq[col], psq); }
    }
}

// ---------------- w3s[d] = sum_j W3[d][j] ----------------
__global__ __launch_bounds__(256) void k_w3s(const float* __restrict__ W3,
                                             float* __restrict__ w3s)
{
    int t = threadIdx.x;
    int row = blockIdx.x * 16 + (t >> 4), sub = t & 15;
    float acc = 0.f;
    for (int i = 0; i < 32; ++i) acc += W3[(long)row * H_SZ + sub + i * 16];
#pragma unroll
    for (int s = 8; s; s >>= 1) acc += __shfl_xor(acc, s, 16);
    if (sub == 0) w3s[row] = acc;
}

// ---------------- final: scores = lr + (a3*r2+c3)·w3s + sum(b3) ----------------
__global__ __launch_bounds__(256) void k_final(
    const unsigned short* __restrict__ r2, const float* __restrict__ a3,
    const float* __restrict__ c3, const float* __restrict__ w3s,
    const float* __restrict__ b3, const float* __restrict__ lr_score,
    float* __restrict__ out)
{
    int t = threadIdx.x, w = t >> 6, l = t & 63;
    int b = blockIdx.x * 4 + w;
    float acc = 0.f;
#pragma unroll
    for (int i = 0; i < 8; ++i) {
        int e = i * 64 + l;
        float v = a3[e] * b2f(r2[(long)b * H_SZ + e]) + c3[e];
        acc += v * w3s[e] + b3[e];
    }
    for (int s = 32; s; s >>= 1) acc += __shfl_down(acc, s, 64);
    if (l == 0) out[b] = lr_score[b] + acc;
}

// ---------------- launcher ----------------
extern "C" void kernel_launch(void* const* d_in, const int* in_sizes, int n_in,
                              void* d_out, int out_size, void* d_ws, size_t ws_size,
                              hipStream_t stream) {
    const int*   st_ids = (const int*)d_in[0];
    const int*   dy_ids = (const int*)d_in[1];
    const int*   dy_len = (const int*)d_in[2];
    const float* st_emb = (const float*)d_in[3];
    const float* dy_emb = (const float*)d_in[4];
    const float* st_lr  = (const float*)d_in[5];
    const float* dy_lr  = (const float*)d_in[6];
    const float* bias   = (const float*)d_in[7];
    const float* bn1_g  = (const float*)d_in[8];
    const float* bn1_b  = (const float*)d_in[9];
    const float* W1     = (const float*)d_in[10];
    const float* b1     = (const float*)d_in[11];
    const float* bn2_g  = (const float*)d_in[12];
    const float* bn2_b  = (const float*)d_in[13];
    const float* W2     = (const float*)d_in[14];
    const float* b2     = (const float*)d_in[15];
    const float* bn3_g  = (const float*)d_in[16];
    const float* bn3_b  = (const float*)d_in[17];
    const float* W3     = (const float*)d_in[18];
    const float* b3     = (const float*)d_in[19];
    // d_in[20..23] feed only the dead final layer — skipped.

    char* ws = (char*)d_ws;
    size_t off = 0;
    auto alloc = [&](size_t bytes) -> char* {
        char* p = ws + off;
        off = (off + bytes + 255) & ~(size_t)255;
        return p;
    };
    float*          all_emb = (float*)alloc((size_t)B_SZ * 480 * 4);
    unsigned short* x16     = (unsigned short*)alloc((size_t)B_SZ * KP1 * 2);
    unsigned short* w1t     = (unsigned short*)alloc((size_t)H_SZ * KP1 * 2);
    unsigned short* r1      = (unsigned short*)alloc((size_t)B_SZ * H_SZ * 2);
    unsigned short* w2t     = (unsigned short*)alloc((size_t)H_SZ * H_SZ * 2);
    unsigned short* r2      = (unsigned short*)alloc((size_t)B_SZ * H_SZ * 2);
    float*          lr_sc   = (float*)alloc(B_SZ * 4);
    char* zstart = ws + off;
    float* s1   = (float*)alloc(KP1 * 4);
    float* s1q  = (float*)alloc(KP1 * 4);
    float* con1 = (float*)alloc(H_SZ * 4);
    float* s2   = (float*)alloc(H_SZ * 4);
    float* s2q  = (float*)alloc(H_SZ * 4);
    float* con2 = (float*)alloc(H_SZ * 4);
    float* s3   = (float*)alloc(H_SZ * 4);
    float* s3q  = (float*)alloc(H_SZ * 4);
    size_t zbytes = (size_t)((ws + off) - zstart);
    float* a1 = (float*)alloc(KP1 * 4);
    float* c1 = (float*)alloc(KP1 * 4);
    float* a2 = (float*)alloc(H_SZ * 4);
    float* c2 = (float*)alloc(H_SZ * 4);
    float* a3 = (float*)alloc(H_SZ * 4);
    float* c3 = (float*)alloc(H_SZ * 4);
    float* w3s = (float*)alloc(H_SZ * 4);
    int* pi = (int*)alloc(NPAIR * 4);
    int* pj = (int*)alloc(NPAIR * 4);

    hipMemsetAsync(zstart, 0, zbytes, stream);
    k_pairs<<<1, 64, 0, stream>>>(pi, pj);
    k_stemb<<<(B_SZ * F_ST * 4) / 256, 256, 0, stream>>>(st_ids, st_emb, all_emb);
    k_dyemb<<<(B_SZ * F_DY) / 8, 512, 0, stream>>>(dy_ids, dy_len, dy_emb, all_emb);
    k_lr<<<B_SZ / 8, 512, 0, stream>>>(st_ids, dy_ids, dy_len, st_lr, dy_lr,
                                       bias, lr_sc);
    k_x<<<B_SZ / 16, 256, 0, stream>>>(all_emb, pi, pj, x16, s1, s1q);
    k_fold<<<28, 256, 0, stream>>>(s1, s1q, bn1_g, bn1_b, a1, c1, DIN);
    k_w1t<<<(872 * 512) / 256, 256, 0, stream>>>(W1, a1, c1, w1t, con1);
    k_gemm<<<dim3(8, 32), 512, 0, stream>>>(x16, w1t, con1, b1, r1, s2, s2q, KP1);
    k_fold<<<2, 256, 0, stream>>>(s2, s2q, bn2_g, bn2_b, a2, c2, H_SZ);
    k_w2t<<<(64 * 512) / 256, 256, 0, stream>>>(W2, a2, c2, w2t, con2);
    k_gemm<<<dim3(8, 32), 512, 0, stream>>>(r1, w2t, con2, b2, r2, s3, s3q, H_SZ);
    k_fold<<<2, 256, 0, stream>>>(s3, s3q, bn3_g, bn3_b, a3, c3, H_SZ);
    k_w3s<<<32, 256, 0, stream>>>(W3, w3s);
    k_final<<<B_SZ / 4, 256, 0, stream>>>(r2, a3, c3, w3s, b3, lr_sc, (float*)d_out);
}

// Round 5
// 435.529 us; speedup vs baseline: 1.5804x; 1.0076x over previous
//
#include <hip/hip_runtime.h>

// ---------------- common helpers ----------------
typedef __attribute__((ext_vector_type(8))) short short8;
typedef __attribute__((ext_vector_type(4))) float f32x4;

__device__ __forceinline__ unsigned short f2b(float f) {
    union { float f; unsigned u; } uf; uf.f = f;
    unsigned r = uf.u + 0x7fffu + ((uf.u >> 16) & 1u);   // RNE, finite inputs
    return (unsigned short)(r >> 16);
}
__device__ __forceinline__ float b2f(unsigned short b) {
    union { unsigned u; float f; } uf; uf.u = ((unsigned)b) << 16;
    return uf.f;
}
__device__ __forceinline__ void gload_lds16(const void* g, void* l) {
    __builtin_amdgcn_global_load_lds(
        (const __attribute__((address_space(1))) void*)g,
        (__attribute__((address_space(3))) void*)l,
        16, 0, 0);
}

#define B_SZ 4096
#define F_ST 20
#define F_DY 10
#define MLEN 50
#define E_SZ 16
#define F_ALL 30
#define NPAIR 435
#define DIN 6960
#define KP 7168            /* DIN zero-padded: 224 K-steps of 32; 896/k-split */
#define H_SZ 512
#define BN_EPS 1e-5f

// ---------------- pair table ----------------
__global__ void k_pairs(int* pi, int* pj) {
    int t = threadIdx.x;
    for (int p = t; p < NPAIR; p += 64) {
        int i = 0, rem = p;
        while (rem >= (F_ALL - 1) - i) { rem -= (F_ALL - 1) - i; ++i; }
        pi[p] = i; pj[p] = i + 1 + rem;
    }
}

// ---------------- static embedding gather (float4 per thread) ----------------
__global__ __launch_bounds__(256) void k_stemb(
    const int* __restrict__ st_ids, const float* __restrict__ st_emb,
    float* __restrict__ all_emb)
{
    int idx = blockIdx.x * 256 + threadIdx.x;    // (b*F_ST+f)*4 + e4
    int e4 = idx & 3, bf = idx >> 2;
    int b = bf / F_ST, f = bf % F_ST;
    int id = st_ids[bf];
    f32x4 v = *(const f32x4*)(st_emb + (long)id * E_SZ + e4 * 4);
    *(f32x4*)(all_emb + ((long)b * F_ALL + f) * E_SZ + e4 * 4) = v;
}

// ------- dynamic masked-mean: one wave per (b,f); ids broadcast via shfl -----
// FIX vs rounds 3/4: uniform trip count so every __shfl executes with ALL
// lanes active (ds_bpermute honors EXEC on the data-supply side — reading
// from an exec-masked-off lane is undefined). Accumulation is predicated.
__global__ __launch_bounds__(512) void k_dyemb(
    const int* __restrict__ dy_ids, const int* __restrict__ dy_len,
    const float* __restrict__ dy_emb, float* __restrict__ all_emb)
{
    int gw = blockIdx.x * 8 + (threadIdx.x >> 6);   // wave id = b*F_DY + f
    int l = threadIdx.x & 63;
    int b = gw / F_DY, f = gw - b * F_DY;
    int len = dy_len[b * F_DY + f]; if (len < 1) len = 1;   // wave-uniform
    const int* ids = dy_ids + ((long)b * F_DY + f) * MLEN;
    int idv = (l < MLEN) ? ids[l] : 0;              // coalesced, one load/lane
    int e = l & 15, mq = l >> 4;
    int iters = (len + 3) >> 2;                     // wave-uniform trip count
    float acc = 0.f;
    for (int j = 0; j < iters; ++j) {
        int m = mq + (j << 2);                      // m <= 3+4*12 = 51 < 64
        int id = __shfl(idv, m, 64);                // all 64 lanes active
        if (m < len)
            acc += dy_emb[(long)id * E_SZ + e];
    }
    acc += __shfl_xor(acc, 16, 64);
    acc += __shfl_xor(acc, 32, 64);
    if (l < 16)
        all_emb[((long)b * F_ALL + F_ST + f) * E_SZ + e] = acc / (float)len;
}

// ---------------- linear (lr) terms: one wave per batch row ----------------
__global__ __launch_bounds__(512) void k_lr(
    const int* __restrict__ st_ids, const int* __restrict__ dy_ids,
    const int* __restrict__ dy_len, const float* __restrict__ st_lr,
    const float* __restrict__ dy_lr, const float* __restrict__ bias,
    float* __restrict__ lr_score)
{
    int w = threadIdx.x >> 6, l = threadIdx.x & 63;
    int b = blockIdx.x * 8 + w;
    float acc = 0.f;
    if (l < F_ST) acc += st_lr[st_ids[b * F_ST + l]];
#pragma unroll
    for (int i = 0; i < 8; ++i) {                   // 10 fields x 50 slots = 500
        int idx = i * 64 + l;
        if (idx < F_DY * MLEN) {
            int f = idx / MLEN, m = idx - f * MLEN;
            int len = dy_len[b * F_DY + f]; if (len < 1) len = 1;
            if (m < len)
                acc += dy_lr[dy_ids[((long)b * F_DY + f) * MLEN + m]];
        }
    }
    for (int s = 32; s; s >>= 1) acc += __shfl_down(acc, s, 64);
    if (l == 0) lr_score[b] = bias[0] + acc;
}

// ---------------- pairwise products -> x (bf16) + BN1 stats ----------------
__global__ __launch_bounds__(256) void k_x(
    const float* __restrict__ all_emb, const int* __restrict__ pi,
    const int* __restrict__ pj, unsigned short* __restrict__ x16,
    float* __restrict__ s1, float* __restrict__ s1q)
{
    __shared__ float es[16 * 480];
    int t = threadIdx.x, b0 = blockIdx.x * 16;
    for (int idx = t; idx < 16 * 480; idx += 256)
        es[idx] = all_emb[(long)b0 * 480 + idx];

    int ci[28], cj[28];
#pragma unroll
    for (int k = 0; k < 28; ++k) {
        int d = t + (k << 8);
        if (d < DIN) {
            int p = d >> 4, e = d & 15;
            ci[k] = pi[p] * E_SZ + e;
            cj[k] = pj[p] * E_SZ + e;
        } else { ci[k] = -1; cj[k] = 0; }
    }
    float sum[28], sq[28];
#pragma unroll
    for (int k = 0; k < 28; ++k) { sum[k] = 0.f; sq[k] = 0.f; }
    __syncthreads();

    for (int r = 0; r < 16; ++r) {
        const float* row = &es[r * 480];
        long ob = (long)(b0 + r) * KP;
#pragma unroll
        for (int k = 0; k < 28; ++k) {
            int d = t + (k << 8);
            if (ci[k] >= 0) {
                float v = row[ci[k]] * row[cj[k]];
                unsigned short h = f2b(v);
                x16[ob + d] = h;
                float vb = b2f(h);
                sum[k] += vb; sq[k] += vb * vb;
            } else {
                x16[ob + d] = 0;           // K padding
            }
        }
    }
#pragma unroll
    for (int k = 0; k < 28; ++k) {
        int d = t + (k << 8);
        if (ci[k] >= 0) { atomicAdd(&s1[d], sum[k]); atomicAdd(&s1q[d], sq[k]); }
    }
}

// ---------------- BN fold: a = g*rsqrt(var+eps), c = b - mean*a ----------------
__global__ void k_fold(const float* __restrict__ s, const float* __restrict__ sqs,
                       const float* __restrict__ g, const float* __restrict__ bb,
                       float* __restrict__ a, float* __restrict__ c, int n)
{
    int d = blockIdx.x * 256 + threadIdx.x;
    if (d < n) {
        float m = s[d] * (1.f / 4096.f);
        float var = sqs[d] * (1.f / 4096.f) - m * m;
        float av = g[d] * rsqrtf(var + BN_EPS);
        a[d] = av; c[d] = bb[d] - m * av;
    }
}

// ---------------- W1^T cast + const1 fold (w1t[n][k] = a1[k]*W1[k][n]) --------
__global__ __launch_bounds__(256) void k_w1t(
    const float* __restrict__ W1, const float* __restrict__ a1,
    const float* __restrict__ c1, unsigned short* __restrict__ w1t,
    float* __restrict__ con)
{
    int gi = blockIdx.x * 256 + threadIdx.x;   // 896*512 groups
    int kg = gi >> 9, n = gi & 511;
    short8 out; float cacc = 0.f;
#pragma unroll
    for (int i = 0; i < 8; ++i) {
        int k = kg * 8 + i;
        if (k < DIN) {
            float w = W1[(long)k * H_SZ + n];
            out[i] = (short)f2b(a1[k] * w);
            cacc += c1[k] * w;
        } else out[i] = 0;
    }
    *(short8*)(w1t + (long)n * KP + kg * 8) = out;
    atomicAdd(&con[n], cacc);
}

// ---------------- W2^T cast + const2 ----------------
__global__ __launch_bounds__(256) void k_w2t(
    const float* __restrict__ W2, const float* __restrict__ a2,
    const float* __restrict__ c2, unsigned short* __restrict__ w2t,
    float* __restrict__ con)
{
    int gi = blockIdx.x * 256 + threadIdx.x;   // 64*512 groups
    int kg = gi >> 9, n = gi & 511;
    short8 out; float cacc = 0.f;
#pragma unroll
    for (int i = 0; i < 8; ++i) {
        int k = kg * 8 + i;
        float w = W2[(long)k * H_SZ + n];
        out[i] = (short)f2b(a2[k] * w);
        cacc += c2[k] * w;
    }
    *(short8*)(w2t + (long)n * H_SZ + kg * 8) = out;
    atomicAdd(&con[n], cacc);
}

// ======== k_gemm1: split-K bf16 MFMA (round-2 k_gemm skeleton) ==============
// tile 128(M) x 64(N), k-slice 896 per blockIdx.z; fp32 atomicAdd to accbuf.
__global__ __launch_bounds__(512) void k_gemm1(
    const unsigned short* __restrict__ A, const unsigned short* __restrict__ Bt,
    float* __restrict__ accbuf)
{
    __shared__ __align__(16) short As[128 * 32];
    __shared__ __align__(16) short Bs[64 * 32];
    const int t = threadIdx.x;
    const int w = t >> 6, l = t & 63;
    const int wm = w >> 1, wn = w & 1;
    const int lm = l & 15, lq = l >> 4;
    const int row0 = blockIdx.y * 128;
    const int col0 = blockIdx.x * 64;
    const int k0 = blockIdx.z * (KP / 8);

    const unsigned short* gA = A + (long)(row0 + (t >> 2)) * KP + k0 + ((t & 3) * 8);
    const unsigned short* gB = Bt + (long)(col0 + ((t >> 2) & 63)) * KP + k0 + ((t & 3) * 8);
    short* AsW = As + w * 512;            // wave-uniform LDS dest
    short* BsW = Bs + w * 512;

    const short* aBase0 = As + (wm * 32 + lm) * 32 + lq * 8;
    const short* aBase1 = aBase0 + 16 * 32;
    const short* bBase0 = Bs + (wn * 32 + lm) * 32 + lq * 8;
    const short* bBase1 = bBase0 + 16 * 32;

    f32x4 acc00 = {0.f,0.f,0.f,0.f}, acc01 = acc00, acc10 = acc00, acc11 = acc00;

    for (int kt = 0; kt < 28; ++kt) {
        gload_lds16(gA, AsW);
        if (t < 256) gload_lds16(gB, BsW);
        __syncthreads();
        short8 af0 = *(const short8*)aBase0;
        short8 af1 = *(const short8*)aBase1;
        short8 bf0 = *(const short8*)bBase0;
        short8 bf1 = *(const short8*)bBase1;
        acc00 = __builtin_amdgcn_mfma_f32_16x16x32_bf16(af0, bf0, acc00, 0, 0, 0);
        acc01 = __builtin_amdgcn_mfma_f32_16x16x32_bf16(af0, bf1, acc01, 0, 0, 0);
        acc10 = __builtin_amdgcn_mfma_f32_16x16x32_bf16(af1, bf0, acc10, 0, 0, 0);
        acc11 = __builtin_amdgcn_mfma_f32_16x16x32_bf16(af1, bf1, acc11, 0, 0, 0);
        __syncthreads();
        gA += 32; gB += 32;
    }

    f32x4 accs[2][2] = {{acc00, acc01}, {acc10, acc11}};
#pragma unroll
    for (int ni = 0; ni < 2; ++ni) {
        int col = col0 + wn * 32 + ni * 16 + lm;
#pragma unroll
        for (int mi = 0; mi < 2; ++mi) {
            int rbase = row0 + wm * 32 + mi * 16 + lq * 4;
#pragma unroll
            for (int r = 0; r < 4; ++r)
                atomicAdd(&accbuf[(long)(rbase + r) * H_SZ + col], accs[mi][ni][r]);
        }
    }
}

// ============ k_ep: accbuf -> relu(.+con1+b1) bf16 r1, + BN2 stats ==========
__global__ __launch_bounds__(256) void k_ep(
    const float* __restrict__ accbuf, const float* __restrict__ con1,
    const float* __restrict__ b1, unsigned short* __restrict__ r1,
    float* __restrict__ s2, float* __restrict__ s2q)
{
    __shared__ float con[H_SZ];
    int t = threadIdx.x, r0 = blockIdx.x * 32;
    con[t] = b1[t] + con1[t];
    con[t + 256] = b1[t + 256] + con1[t + 256];
    __syncthreads();
    float a0 = 0.f, q0 = 0.f, a1v = 0.f, q1 = 0.f;
    for (int r = 0; r < 32; ++r) {
        long base = (long)(r0 + r) * H_SZ;
        float v0 = accbuf[base + t] + con[t];
        float v1 = accbuf[base + t + 256] + con[t + 256];
        v0 = v0 > 0.f ? v0 : 0.f;
        v1 = v1 > 0.f ? v1 : 0.f;
        unsigned short h0 = f2b(v0), h1 = f2b(v1);
        r1[base + t] = h0; r1[base + t + 256] = h1;
        float b0 = b2f(h0), b1f = b2f(h1);
        a0 += b0; q0 += b0 * b0; a1v += b1f; q1 += b1f * b1f;
    }
    atomicAdd(&s2[t], a0);        atomicAdd(&s2q[t], q0);
    atomicAdd(&s2[t + 256], a1v); atomicAdd(&s2q[t + 256], q1);
}

// ============ k_gemm2: full-K bf16 MFMA + fused relu + col stats ============
__global__ __launch_bounds__(512) void k_gemm2(
    const unsigned short* __restrict__ A, const unsigned short* __restrict__ Bt,
    const float* __restrict__ cvec, const float* __restrict__ bvec,
    unsigned short* __restrict__ Out, float* __restrict__ ss,
    float* __restrict__ sq)
{
    const int Kp = H_SZ;
    __shared__ __align__(16) short As[128 * 32];
    __shared__ __align__(16) short Bs[64 * 32];
    const int t = threadIdx.x;
    const int w = t >> 6, l = t & 63;
    const int wm = w >> 1, wn = w & 1;
    const int lm = l & 15, lq = l >> 4;
    const int row0 = blockIdx.y * 128;
    const int col0 = blockIdx.x * 64;

    const unsigned short* gA = A + (long)(row0 + (t >> 2)) * Kp + ((t & 3) * 8);
    const unsigned short* gB = Bt + (long)(col0 + ((t >> 2) & 63)) * Kp + ((t & 3) * 8);
    short* AsW = As + w * 512;
    short* BsW = Bs + w * 512;

    const short* aBase0 = As + (wm * 32 + lm) * 32 + lq * 8;
    const short* aBase1 = aBase0 + 16 * 32;
    const short* bBase0 = Bs + (wn * 32 + lm) * 32 + lq * 8;
    const short* bBase1 = bBase0 + 16 * 32;

    f32x4 acc00 = {0.f,0.f,0.f,0.f}, acc01 = acc00, acc10 = acc00, acc11 = acc00;

    for (int kt = 0; kt < Kp / 32; ++kt) {
        gload_lds16(gA, AsW);
        if (t < 256) gload_lds16(gB, BsW);
        __syncthreads();
        short8 af0 = *(const short8*)aBase0;
        short8 af1 = *(const short8*)aBase1;
        short8 bf0 = *(const short8*)bBase0;
        short8 bf1 = *(const short8*)bBase1;
        acc00 = __builtin_amdgcn_mfma_f32_16x16x32_bf16(af0, bf0, acc00, 0, 0, 0);
        acc01 = __builtin_amdgcn_mfma_f32_16x16x32_bf16(af0, bf1, acc01, 0, 0, 0);
        acc10 = __builtin_amdgcn_mfma_f32_16x16x32_bf16(af1, bf0, acc10, 0, 0, 0);
        acc11 = __builtin_amdgcn_mfma_f32_16x16x32_bf16(af1, bf1, acc11, 0, 0, 0);
        __syncthreads();
        gA += 32; gB += 32;
    }

    f32x4 accs[2][2] = {{acc00, acc01}, {acc10, acc11}};
#pragma unroll
    for (int ni = 0; ni < 2; ++ni) {
        int col = col0 + wn * 32 + ni * 16 + lm;
        float cb = cvec[col] + bvec[col];
        float psum = 0.f, psq = 0.f;
#pragma unroll
        for (int mi = 0; mi < 2; ++mi) {
            int rbase = row0 + wm * 32 + mi * 16 + lq * 4;
#pragma unroll
            for (int r = 0; r < 4; ++r) {
                float v = accs[mi][ni][r] + cb;
                v = v > 0.f ? v : 0.f;
                unsigned short h = f2b(v);
                Out[(long)(rbase + r) * H_SZ + col] = h;
                float vb = b2f(h);
                psum += vb; psq += vb * vb;
            }
        }
        psum += __shfl_xor(psum, 16, 64); psum += __shfl_xor(psum, 32, 64);
        psq  += __shfl_xor(psq , 16, 64); psq  += __shfl_xor(psq , 32, 64);
        if (lq == 0) { atomicAdd(&ss[col], psum); atomicAdd(&sq[col], psq); }
    }
}

// ---------------- w3s[d] = sum_j W3[d][j] ----------------
__global__ __launch_bounds__(256) void k_w3s(const float* __restrict__ W3,
                                             float* __restrict__ w3s)
{
    int t = threadIdx.x;
    int row = blockIdx.x * 16 + (t >> 4), sub = t & 15;
    float acc = 0.f;
    for (int i = 0; i < 32; ++i) acc += W3[(long)row * H_SZ + sub + i * 16];
#pragma unroll
    for (int s = 8; s; s >>= 1) acc += __shfl_xor(acc, s, 16);
    if (sub == 0) w3s[row] = acc;
}

// ---------------- final: scores = lr + (a3*r2+c3)·w3s + sum(b3) ----------------
__global__ __launch_bounds__(256) void k_final(
    const unsigned short* __restrict__ r2, const float* __restrict__ a3,
    const float* __restrict__ c3, const float* __restrict__ w3s,
    const float* __restrict__ b3, const float* __restrict__ lr_score,
    float* __restrict__ out)
{
    int t = threadIdx.x, w = t >> 6, l = t & 63;
    int b = blockIdx.x * 4 + w;
    float acc = 0.f;
#pragma unroll
    for (int i = 0; i < 8; ++i) {
        int e = i * 64 + l;
        float v = a3[e] * b2f(r2[(long)b * H_SZ + e]) + c3[e];
        acc += v * w3s[e] + b3[e];
    }
    for (int s = 32; s; s >>= 1) acc += __shfl_down(acc, s, 64);
    if (l == 0) out[b] = lr_score[b] + acc;
}

// ---------------- launcher ----------------
extern "C" void kernel_launch(void* const* d_in, const int* in_sizes, int n_in,
                              void* d_out, int out_size, void* d_ws, size_t ws_size,
                              hipStream_t stream) {
    const int*   st_ids = (const int*)d_in[0];
    const int*   dy_ids = (const int*)d_in[1];
    const int*   dy_len = (const int*)d_in[2];
    const float* st_emb = (const float*)d_in[3];
    const float* dy_emb = (const float*)d_in[4];
    const float* st_lr  = (const float*)d_in[5];
    const float* dy_lr  = (const float*)d_in[6];
    const float* bias   = (const float*)d_in[7];
    const float* bn1_g  = (const float*)d_in[8];
    const float* bn1_b  = (const float*)d_in[9];
    const float* W1     = (const float*)d_in[10];
    const float* b1     = (const float*)d_in[11];
    const float* bn2_g  = (const float*)d_in[12];
    const float* bn2_b  = (const float*)d_in[13];
    const float* W2     = (const float*)d_in[14];
    const float* b2     = (const float*)d_in[15];
    const float* bn3_g  = (const float*)d_in[16];
    const float* bn3_b  = (const float*)d_in[17];
    const float* W3     = (const float*)d_in[18];
    const float* b3     = (const float*)d_in[19];
    // d_in[20..23] feed only the dead final layer — skipped.

    char* ws = (char*)d_ws;
    size_t off = 0;
    auto alloc = [&](size_t bytes) -> char* {
        char* p = ws + off;
        off = (off + bytes + 255) & ~(size_t)255;
        return p;
    };
    // Union region R (8.39 MB), time-multiplexed:
    //   phase 1: all_emb (7.87 MB)   [k_stemb..k_x]
    //   phase 2: accbuf  (8.39 MB)   [memset -> k_gemm1 -> k_ep]
    //   phase 3: r2      (4.19 MB)   [k_gemm2 -> k_final]
    char* R = alloc((size_t)B_SZ * H_SZ * 4);      // 8,388,608 B
    float*          all_emb = (float*)R;
    float*          accbuf  = (float*)R;
    unsigned short* r2      = (unsigned short*)R;

    unsigned short* x16     = (unsigned short*)alloc((size_t)B_SZ * KP * 2);
    unsigned short* w1t     = (unsigned short*)alloc((size_t)H_SZ * KP * 2);
    unsigned short* r1      = (unsigned short*)alloc((size_t)B_SZ * H_SZ * 2);
    unsigned short* w2t     = (unsigned short*)alloc((size_t)H_SZ * H_SZ * 2);
    float*          lr_sc   = (float*)alloc(B_SZ * 4);
    float* a1  = (float*)alloc(KP * 4);
    float* c1  = (float*)alloc(KP * 4);
    float* a2  = (float*)alloc(H_SZ * 4);
    float* c2  = (float*)alloc(H_SZ * 4);
    float* a3  = (float*)alloc(H_SZ * 4);
    float* c3  = (float*)alloc(H_SZ * 4);
    float* w3s = (float*)alloc(H_SZ * 4);
    int* pi = (int*)alloc(NPAIR * 4);
    int* pj = (int*)alloc(NPAIR * 4);
    char* zstart = ws + off;                       // ---- zeroed stats ----
    float* s1   = (float*)alloc(KP * 4);
    float* s1q  = (float*)alloc(KP * 4);
    float* con1 = (float*)alloc(H_SZ * 4);
    float* s2   = (float*)alloc(H_SZ * 4);
    float* s2q  = (float*)alloc(H_SZ * 4);
    float* con2 = (float*)alloc(H_SZ * 4);
    float* s3   = (float*)alloc(H_SZ * 4);
    float* s3q  = (float*)alloc(H_SZ * 4);
    size_t zbytes = (size_t)((ws + off) - zstart);
    // total ws use ≈ 79.3 MB  (< 81.2 MB proven safe in rounds 1-2)

    hipMemsetAsync(zstart, 0, zbytes, stream);
    k_pairs<<<1, 64, 0, stream>>>(pi, pj);
    k_stemb<<<(B_SZ * F_ST * 4) / 256, 256, 0, stream>>>(st_ids, st_emb, all_emb);
    k_dyemb<<<(B_SZ * F_DY) / 8, 512, 0, stream>>>(dy_ids, dy_len, dy_emb, all_emb);
    k_lr<<<B_SZ / 8, 512, 0, stream>>>(st_ids, dy_ids, dy_len, st_lr, dy_lr,
                                       bias, lr_sc);
    k_x<<<B_SZ / 16, 256, 0, stream>>>(all_emb, pi, pj, x16, s1, s1q);
    // all_emb dead; repurpose R as zeroed fp32 accumulator
    hipMemsetAsync(R, 0, (size_t)B_SZ * H_SZ * 4, stream);
    k_fold<<<28, 256, 0, stream>>>(s1, s1q, bn1_g, bn1_b, a1, c1, DIN);
    k_w1t<<<(896 * 512) / 256, 256, 0, stream>>>(W1, a1, c1, w1t, con1);
    k_gemm1<<<dim3(8, 32, 8), 512, 0, stream>>>(x16, w1t, accbuf);
    k_ep<<<128, 256, 0, stream>>>(accbuf, con1, b1, r1, s2, s2q);
    k_fold<<<2, 256, 0, stream>>>(s2, s2q, bn2_g, bn2_b, a2, c2, H_SZ);
    k_w2t<<<128, 256, 0, stream>>>(W2, a2, c2, w2t, con2);
    // accbuf dead; repurpose R as r2
    k_gemm2<<<dim3(8, 32), 512, 0, stream>>>(r1, w2t, con2, b2, r2, s3, s3q);
    k_fold<<<2, 256, 0, stream>>>(s3, s3q, bn3_g, bn3_b, a3, c3, H_SZ);
    k_w3s<<<32, 256, 0, stream>>>(W3, w3s);
    k_final<<<B_SZ / 4, 256, 0, stream>>>(r2, a3, c3, w3s, b3, lr_sc, (float*)d_out);
}

// Round 6
// 418.776 us; speedup vs baseline: 1.6436x; 1.0400x over previous
//
#include <hip/hip_runtime.h>

// ---------------- common helpers ----------------
typedef __attribute__((ext_vector_type(8))) short short8;
typedef __attribute__((ext_vector_type(4))) float f32x4;

__device__ __forceinline__ unsigned short f2b(float f) {
    union { float f; unsigned u; } uf; uf.f = f;
    unsigned r = uf.u + 0x7fffu + ((uf.u >> 16) & 1u);   // RNE, finite inputs
    return (unsigned short)(r >> 16);
}
__device__ __forceinline__ float b2f(unsigned short b) {
    union { unsigned u; float f; } uf; uf.u = ((unsigned)b) << 16;
    return uf.f;
}
__device__ __forceinline__ void gload_lds16(const void* g, void* l) {
    __builtin_amdgcn_global_load_lds(
        (const __attribute__((address_space(1))) void*)g,
        (__attribute__((address_space(3))) void*)l,
        16, 0, 0);
}

#define B_SZ 4096
#define F_ST 20
#define F_DY 10
#define MLEN 50
#define E_SZ 16
#define F_ALL 30
#define NPAIR 435
#define DIN 6960
#define KP 7168            /* DIN zero-padded; 4 k-slices of 1792 (56 steps) */
#define H_SZ 512
#define BN_EPS 1e-5f

// ---------------- static embedding gather (float4 per thread) ----------------
__global__ __launch_bounds__(256) void k_stemb(
    const int* __restrict__ st_ids, const float* __restrict__ st_emb,
    float* __restrict__ all_emb)
{
    int idx = blockIdx.x * 256 + threadIdx.x;    // (b*F_ST+f)*4 + e4
    int e4 = idx & 3, bf = idx >> 2;
    int b = bf / F_ST, f = bf % F_ST;
    int id = st_ids[bf];
    f32x4 v = *(const f32x4*)(st_emb + (long)id * E_SZ + e4 * 4);
    *(f32x4*)(all_emb + ((long)b * F_ALL + f) * E_SZ + e4 * 4) = v;
}

// ------- dynamic masked-mean: one wave per (b,f); ids broadcast via shfl -----
// Uniform trip count: every __shfl executes with ALL lanes active (reading
// from an exec-masked-off source lane is undefined). Accumulation predicated.
__global__ __launch_bounds__(512) void k_dyemb(
    const int* __restrict__ dy_ids, const int* __restrict__ dy_len,
    const float* __restrict__ dy_emb, float* __restrict__ all_emb)
{
    int gw = blockIdx.x * 8 + (threadIdx.x >> 6);   // wave id = b*F_DY + f
    int l = threadIdx.x & 63;
    int b = gw / F_DY, f = gw - b * F_DY;
    int len = dy_len[b * F_DY + f]; if (len < 1) len = 1;   // wave-uniform
    const int* ids = dy_ids + ((long)b * F_DY + f) * MLEN;
    int idv = (l < MLEN) ? ids[l] : 0;              // coalesced, one load/lane
    int e = l & 15, mq = l >> 4;
    int iters = (len + 3) >> 2;                     // wave-uniform trip count
    float acc = 0.f;
    for (int j = 0; j < iters; ++j) {
        int m = mq + (j << 2);                      // m <= 51 < 64
        int id = __shfl(idv, m, 64);                // all 64 lanes active
        if (m < len)
            acc += dy_emb[(long)id * E_SZ + e];
    }
    acc += __shfl_xor(acc, 16, 64);
    acc += __shfl_xor(acc, 32, 64);
    if (l < 16)
        all_emb[((long)b * F_ALL + F_ST + f) * E_SZ + e] = acc / (float)len;
}

// ---------------- linear (lr) terms: one wave per batch row ----------------
__global__ __launch_bounds__(512) void k_lr(
    const int* __restrict__ st_ids, const int* __restrict__ dy_ids,
    const int* __restrict__ dy_len, const float* __restrict__ st_lr,
    const float* __restrict__ dy_lr, const float* __restrict__ bias,
    float* __restrict__ lr_score)
{
    int w = threadIdx.x >> 6, l = threadIdx.x & 63;
    int b = blockIdx.x * 8 + w;
    float acc = 0.f;
    if (l < F_ST) acc += st_lr[st_ids[b * F_ST + l]];
#pragma unroll
    for (int i = 0; i < 8; ++i) {                   // 10 fields x 50 slots = 500
        int idx = i * 64 + l;
        if (idx < F_DY * MLEN) {
            int f = idx / MLEN, m = idx - f * MLEN;
            int len = dy_len[b * F_DY + f]; if (len < 1) len = 1;
            if (m < len)
                acc += dy_lr[dy_ids[((long)b * F_DY + f) * MLEN + m]];
        }
    }
    for (int s = 32; s; s >>= 1) acc += __shfl_down(acc, s, 64);
    if (l == 0) lr_score[b] = bias[0] + acc;
}

// ---------- k_x: pairwise products -> x (bf16, K-padded) + BN1 stats --------
// pair table computed in-kernel (saves a launch)
__global__ __launch_bounds__(256) void k_x(
    const float* __restrict__ all_emb, unsigned short* __restrict__ x16,
    float* __restrict__ s1, float* __restrict__ s1q)
{
    __shared__ float es[16 * 480];
    __shared__ int pip[NPAIR], pjp[NPAIR];
    int t = threadIdx.x, b0 = blockIdx.x * 16;
    for (int p = t; p < NPAIR; p += 256) {
        int i = 0, rem = p;
        while (rem >= (F_ALL - 1) - i) { rem -= (F_ALL - 1) - i; ++i; }
        pip[p] = i; pjp[p] = i + 1 + rem;
    }
    for (int idx = t; idx < 16 * 480; idx += 256)
        es[idx] = all_emb[(long)b0 * 480 + idx];
    __syncthreads();

    int ci[28], cj[28];
#pragma unroll
    for (int k = 0; k < 28; ++k) {
        int d = t + (k << 8);
        if (d < DIN) {
            int p = d >> 4, e = d & 15;
            ci[k] = pip[p] * E_SZ + e;
            cj[k] = pjp[p] * E_SZ + e;
        } else { ci[k] = -1; cj[k] = 0; }
    }
    float sum[28], sq[28];
#pragma unroll
    for (int k = 0; k < 28; ++k) { sum[k] = 0.f; sq[k] = 0.f; }

    for (int r = 0; r < 16; ++r) {
        const float* row = &es[r * 480];
        long ob = (long)(b0 + r) * KP;
#pragma unroll
        for (int k = 0; k < 28; ++k) {
            int d = t + (k << 8);
            if (ci[k] >= 0) {
                float v = row[ci[k]] * row[cj[k]];
                unsigned short h = f2b(v);
                x16[ob + d] = h;
                float vb = b2f(h);
                sum[k] += vb; sq[k] += vb * vb;
            } else {
                x16[ob + d] = 0;           // K padding
            }
        }
    }
#pragma unroll
    for (int k = 0; k < 28; ++k) {
        int d = t + (k << 8);
        if (ci[k] >= 0) { atomicAdd(&s1[d], sum[k]); atomicAdd(&s1q[d], sq[k]); }
    }
}

// ============ k_prep: BN1 fold (blocks 0..27) + W3 row-sums (28..59) ========
__global__ __launch_bounds__(256) void k_prep(
    const float* __restrict__ s, const float* __restrict__ sqs,
    const float* __restrict__ g, const float* __restrict__ bb,
    float* __restrict__ a, float* __restrict__ c,
    const float* __restrict__ W3, float* __restrict__ w3s)
{
    int t = threadIdx.x;
    if (blockIdx.x < 28) {
        int d = blockIdx.x * 256 + t;
        if (d < DIN) {
            float m = s[d] * (1.f / 4096.f);
            float var = sqs[d] * (1.f / 4096.f) - m * m;
            float av = g[d] * rsqrtf(var + BN_EPS);
            a[d] = av; c[d] = bb[d] - m * av;
        }
    } else {
        int row = (blockIdx.x - 28) * 16 + (t >> 4), sub = t & 15;
        float acc = 0.f;
        for (int i = 0; i < 32; ++i) acc += W3[(long)row * H_SZ + sub + i * 16];
#pragma unroll
        for (int sh = 8; sh; sh >>= 1) acc += __shfl_xor(acc, sh, 16);
        if (sub == 0) w3s[row] = acc;
    }
}

// ---------------- W1^T cast + const1 fold (w1t[n][k] = a1[k]*W1[k][n]) --------
__global__ __launch_bounds__(256) void k_w1t(
    const float* __restrict__ W1, const float* __restrict__ a1,
    const float* __restrict__ c1, unsigned short* __restrict__ w1t,
    float* __restrict__ con)
{
    int gi = blockIdx.x * 256 + threadIdx.x;   // 896*512 groups
    int kg = gi >> 9, n = gi & 511;
    short8 out; float cacc = 0.f;
#pragma unroll
    for (int i = 0; i < 8; ++i) {
        int k = kg * 8 + i;
        if (k < DIN) {
            float w = W1[(long)k * H_SZ + n];
            out[i] = (short)f2b(a1[k] * w);
            cacc += c1[k] * w;
        } else out[i] = 0;
    }
    *(short8*)(w1t + (long)n * KP + kg * 8) = out;
    atomicAdd(&con[n], cacc);
}

// ======== k_gemm1: output-stationary split-K bf16 MFMA ======================
// tile M=64 x N=512 (full width); grid (64 mtiles, 4 ksplit); 512 thr = 8
// waves, each owning a 64x64 output tile. A read exactly once.
__global__ __launch_bounds__(512, 2) void k_gemm1(
    const unsigned short* __restrict__ A, const unsigned short* __restrict__ Bt,
    float* __restrict__ accbuf)
{
    __shared__ __align__(16) short As[64 * 32];    // 4 KB
    __shared__ __align__(16) short Bs[512 * 32];   // 32 KB
    const int t = threadIdx.x;
    const int w = t >> 6, l = t & 63;
    const int lm = l & 15, lq = l >> 4;
    const int row0 = blockIdx.x * 64;
    const int k0 = blockIdx.y * (KP / 4);          // 1792-wide K slice

    const unsigned short* gA = A + (long)(row0 + (t >> 2)) * KP + k0 + ((t & 3) * 8);
    const unsigned short* gB = Bt + (long)(t >> 2) * KP + k0 + ((t & 3) * 8);
    short* AsW = As + w * 512;             // valid for w<4 (t<256)
    short* BsW = Bs + w * 512;

    f32x4 acc[4][4];
#pragma unroll
    for (int mi = 0; mi < 4; ++mi)
#pragma unroll
        for (int ni = 0; ni < 4; ++ni) acc[mi][ni] = (f32x4){0.f,0.f,0.f,0.f};

    for (int kt = 0; kt < 56; ++kt) {
        if (t < 256) gload_lds16(gA, AsW);          // A: 64 rows x 32 k
#pragma unroll
        for (int c = 0; c < 4; ++c)                 // B: 512 rows x 32 k
            gload_lds16(gB + (long)c * 128 * KP, BsW + c * 4096);
        __syncthreads();
        short8 af[4];
#pragma unroll
        for (int mi = 0; mi < 4; ++mi)
            af[mi] = *(const short8*)(As + (mi * 16 + lm) * 32 + lq * 8);
#pragma unroll
        for (int ni = 0; ni < 4; ++ni) {
            short8 bf = *(const short8*)(Bs + (w * 64 + ni * 16 + lm) * 32 + lq * 8);
#pragma unroll
            for (int mi = 0; mi < 4; ++mi)
                acc[mi][ni] = __builtin_amdgcn_mfma_f32_16x16x32_bf16(
                    af[mi], bf, acc[mi][ni], 0, 0, 0);
        }
        __syncthreads();
        gA += 32; gB += 32;
    }

    // C/D layout: col = lane&15 (n), row = (lane>>4)*4 + reg (m)
#pragma unroll
    for (int ni = 0; ni < 4; ++ni) {
        int col = w * 64 + ni * 16 + lm;
#pragma unroll
        for (int mi = 0; mi < 4; ++mi) {
            int rbase = row0 + mi * 16 + lq * 4;
#pragma unroll
            for (int r = 0; r < 4; ++r)
                atomicAdd(&accbuf[(long)(rbase + r) * H_SZ + col], acc[mi][ni][r]);
        }
    }
}

// ============ k_ep: accbuf -> relu(.+con1+b1) bf16 r1, + BN2 stats ==========
__global__ __launch_bounds__(256) void k_ep(
    const float* __restrict__ accbuf, const float* __restrict__ con1,
    const float* __restrict__ b1, unsigned short* __restrict__ r1,
    float* __restrict__ s2, float* __restrict__ s2q)
{
    __shared__ float con[H_SZ];
    int t = threadIdx.x, r0 = blockIdx.x * 32;
    con[t] = b1[t] + con1[t];
    con[t + 256] = b1[t + 256] + con1[t + 256];
    __syncthreads();
    float a0 = 0.f, q0 = 0.f, a1v = 0.f, q1 = 0.f;
    for (int r = 0; r < 32; ++r) {
        long base = (long)(r0 + r) * H_SZ;
        float v0 = accbuf[base + t] + con[t];
        float v1 = accbuf[base + t + 256] + con[t + 256];
        v0 = v0 > 0.f ? v0 : 0.f;
        v1 = v1 > 0.f ? v1 : 0.f;
        unsigned short h0 = f2b(v0), h1 = f2b(v1);
        r1[base + t] = h0; r1[base + t + 256] = h1;
        float b0 = b2f(h0), b1f = b2f(h1);
        a0 += b0; q0 += b0 * b0; a1v += b1f; q1 += b1f * b1f;
    }
    atomicAdd(&s2[t], a0);        atomicAdd(&s2q[t], q0);
    atomicAdd(&s2[t + 256], a1v); atomicAdd(&s2q[t + 256], q1);
}

// ============ k_w2t: inline BN2 fold + W2^T bf16 cast + con2 ================
__global__ __launch_bounds__(256) void k_w2t(
    const float* __restrict__ W2, const float* __restrict__ s2,
    const float* __restrict__ s2q, const float* __restrict__ g2,
    const float* __restrict__ bb2, unsigned short* __restrict__ w2t,
    float* __restrict__ con)
{
    int gi = blockIdx.x * 256 + threadIdx.x;   // 64 kg * 512 n
    int kg = gi >> 9, n = gi & 511;
    short8 out; float cacc = 0.f;
#pragma unroll
    for (int i = 0; i < 8; ++i) {
        int k = kg * 8 + i;
        float m = s2[k] * (1.f / 4096.f);
        float var = s2q[k] * (1.f / 4096.f) - m * m;
        float av = g2[k] * rsqrtf(var + BN_EPS);
        float cv = bb2[k] - m * av;
        float w = W2[(long)k * H_SZ + n];
        out[i] = (short)f2b(av * w);
        cacc += cv * w;
    }
    *(short8*)(w2t + (long)n * H_SZ + kg * 8) = out;
    atomicAdd(&con[n], cacc);
}

// ============ k_gemm2: full-K bf16 MFMA + fused relu + col stats ============
__global__ __launch_bounds__(512) void k_gemm2(
    const unsigned short* __restrict__ A, const unsigned short* __restrict__ Bt,
    const float* __restrict__ cvec, const float* __restrict__ bvec,
    unsigned short* __restrict__ Out, float* __restrict__ ss,
    float* __restrict__ sq)
{
    const int Kp = H_SZ;
    __shared__ __align__(16) short As[128 * 32];
    __shared__ __align__(16) short Bs[64 * 32];
    const int t = threadIdx.x;
    const int w = t >> 6, l = t & 63;
    const int wm = w >> 1, wn = w & 1;
    const int lm = l & 15, lq = l >> 4;
    const int row0 = blockIdx.y * 128;
    const int col0 = blockIdx.x * 64;

    const unsigned short* gA = A + (long)(row0 + (t >> 2)) * Kp + ((t & 3) * 8);
    const unsigned short* gB = Bt + (long)(col0 + ((t >> 2) & 63)) * Kp + ((t & 3) * 8);
    short* AsW = As + w * 512;
    short* BsW = Bs + w * 512;

    const short* aBase0 = As + (wm * 32 + lm) * 32 + lq * 8;
    const short* aBase1 = aBase0 + 16 * 32;
    const short* bBase0 = Bs + (wn * 32 + lm) * 32 + lq * 8;
    const short* bBase1 = bBase0 + 16 * 32;

    f32x4 acc00 = {0.f,0.f,0.f,0.f}, acc01 = acc00, acc10 = acc00, acc11 = acc00;

    for (int kt = 0; kt < Kp / 32; ++kt) {
        gload_lds16(gA, AsW);
        if (t < 256) gload_lds16(gB, BsW);
        __syncthreads();
        short8 af0 = *(const short8*)aBase0;
        short8 af1 = *(const short8*)aBase1;
        short8 bf0 = *(const short8*)bBase0;
        short8 bf1 = *(const short8*)bBase1;
        acc00 = __builtin_amdgcn_mfma_f32_16x16x32_bf16(af0, bf0, acc00, 0, 0, 0);
        acc01 = __builtin_amdgcn_mfma_f32_16x16x32_bf16(af0, bf1, acc01, 0, 0, 0);
        acc10 = __builtin_amdgcn_mfma_f32_16x16x32_bf16(af1, bf0, acc10, 0, 0, 0);
        acc11 = __builtin_amdgcn_mfma_f32_16x16x32_bf16(af1, bf1, acc11, 0, 0, 0);
        __syncthreads();
        gA += 32; gB += 32;
    }

    f32x4 accs[2][2] = {{acc00, acc01}, {acc10, acc11}};
#pragma unroll
    for (int ni = 0; ni < 2; ++ni) {
        int col = col0 + wn * 32 + ni * 16 + lm;
        float cb = cvec[col] + bvec[col];
        float psum = 0.f, psq = 0.f;
#pragma unroll
        for (int mi = 0; mi < 2; ++mi) {
            int rbase = row0 + wm * 32 + mi * 16 + lq * 4;
#pragma unroll
            for (int r = 0; r < 4; ++r) {
                float v = accs[mi][ni][r] + cb;
                v = v > 0.f ? v : 0.f;
                unsigned short h = f2b(v);
                Out[(long)(rbase + r) * H_SZ + col] = h;
                float vb = b2f(h);
                psum += vb; psq += vb * vb;
            }
        }
        psum += __shfl_xor(psum, 16, 64); psum += __shfl_xor(psum, 32, 64);
        psq  += __shfl_xor(psq , 16, 64); psq  += __shfl_xor(psq , 32, 64);
        if (lq == 0) { atomicAdd(&ss[col], psum); atomicAdd(&sq[col], psq); }
    }
}

// ============ k_final: inline BN3 fold + GEMV + lr ==========================
__global__ __launch_bounds__(256) void k_final(
    const unsigned short* __restrict__ r2, const float* __restrict__ s3,
    const float* __restrict__ s3q, const float* __restrict__ g3,
    const float* __restrict__ bb3, const float* __restrict__ w3s,
    const float* __restrict__ b3, const float* __restrict__ lr_score,
    float* __restrict__ out)
{
    int t = threadIdx.x, w = t >> 6, l = t & 63;
    int b = blockIdx.x * 4 + w;
    float acc = 0.f;
#pragma unroll
    for (int i = 0; i < 8; ++i) {
        int e = i * 64 + l;
        float m = s3[e] * (1.f / 4096.f);
        float var = s3q[e] * (1.f / 4096.f) - m * m;
        float a3 = g3[e] * rsqrtf(var + BN_EPS);
        float c3 = bb3[e] - m * a3;
        float v = a3 * b2f(r2[(long)b * H_SZ + e]) + c3;
        acc += v * w3s[e] + b3[e];
    }
    for (int s = 32; s; s >>= 1) acc += __shfl_down(acc, s, 64);
    if (l == 0) out[b] = lr_score[b] + acc;
}

// ---------------- launcher ----------------
extern "C" void kernel_launch(void* const* d_in, const int* in_sizes, int n_in,
                              void* d_out, int out_size, void* d_ws, size_t ws_size,
                              hipStream_t stream) {
    const int*   st_ids = (const int*)d_in[0];
    const int*   dy_ids = (const int*)d_in[1];
    const int*   dy_len = (const int*)d_in[2];
    const float* st_emb = (const float*)d_in[3];
    const float* dy_emb = (const float*)d_in[4];
    const float* st_lr  = (const float*)d_in[5];
    const float* dy_lr  = (const float*)d_in[6];
    const float* bias   = (const float*)d_in[7];
    const float* bn1_g  = (const float*)d_in[8];
    const float* bn1_b  = (const float*)d_in[9];
    const float* W1     = (const float*)d_in[10];
    const float* b1     = (const float*)d_in[11];
    const float* bn2_g  = (const float*)d_in[12];
    const float* bn2_b  = (const float*)d_in[13];
    const float* W2     = (const float*)d_in[14];
    const float* b2     = (const float*)d_in[15];
    const float* bn3_g  = (const float*)d_in[16];
    const float* bn3_b  = (const float*)d_in[17];
    const float* W3     = (const float*)d_in[18];
    const float* b3     = (const float*)d_in[19];
    // d_in[20..23] feed only the dead final layer — skipped.

    char* ws = (char*)d_ws;
    size_t off = 0;
    auto alloc = [&](size_t bytes) -> char* {
        char* p = ws + off;
        off = (off + bytes + 255) & ~(size_t)255;
        return p;
    };
    // Union region R (8.39 MB), time-multiplexed:
    //   phase 1: all_emb (7.87 MB)   [k_stemb..k_x]
    //   phase 2: accbuf  (8.39 MB)   [memset -> k_gemm1 -> k_ep]
    //   phase 3: r2      (4.19 MB)   [k_gemm2 -> k_final]
    char* R = alloc((size_t)B_SZ * H_SZ * 4);      // 8,388,608 B
    float*          all_emb = (float*)R;
    float*          accbuf  = (float*)R;
    unsigned short* r2      = (unsigned short*)R;

    unsigned short* x16     = (unsigned short*)alloc((size_t)B_SZ * KP * 2);
    unsigned short* w1t     = (unsigned short*)alloc((size_t)H_SZ * KP * 2);
    unsigned short* r1      = (unsigned short*)alloc((size_t)B_SZ * H_SZ * 2);
    unsigned short* w2t     = (unsigned short*)alloc((size_t)H_SZ * H_SZ * 2);
    float*          lr_sc   = (float*)alloc(B_SZ * 4);
    float* a1  = (float*)alloc(KP * 4);
    float* c1  = (float*)alloc(KP * 4);
    float* w3s = (float*)alloc(H_SZ * 4);
    char* zstart = ws + off;                       // ---- zeroed stats ----
    float* s1   = (float*)alloc(KP * 4);
    float* s1q  = (float*)alloc(KP * 4);
    float* con1 = (float*)alloc(H_SZ * 4);
    float* s2   = (float*)alloc(H_SZ * 4);
    float* s2q  = (float*)alloc(H_SZ * 4);
    float* con2 = (float*)alloc(H_SZ * 4);
    float* s3   = (float*)alloc(H_SZ * 4);
    float* s3q  = (float*)alloc(H_SZ * 4);
    size_t zbytes = (size_t)((ws + off) - zstart);
    // total ws use ≈ 79.3 MB (< 81.2 MB proven safe)

    hipMemsetAsync(zstart, 0, zbytes, stream);
    k_stemb<<<(B_SZ * F_ST * 4) / 256, 256, 0, stream>>>(st_ids, st_emb, all_emb);
    k_dyemb<<<(B_SZ * F_DY) / 8, 512, 0, stream>>>(dy_ids, dy_len, dy_emb, all_emb);
    k_lr<<<B_SZ / 8, 512, 0, stream>>>(st_ids, dy_ids, dy_len, st_lr, dy_lr,
                                       bias, lr_sc);
    k_x<<<B_SZ / 16, 256, 0, stream>>>(all_emb, x16, s1, s1q);
    // all_emb dead; repurpose R as zeroed fp32 accumulator
    hipMemsetAsync(R, 0, (size_t)B_SZ * H_SZ * 4, stream);
    k_prep<<<60, 256, 0, stream>>>(s1, s1q, bn1_g, bn1_b, a1, c1, W3, w3s);
    k_w1t<<<(896 * 512) / 256, 256, 0, stream>>>(W1, a1, c1, w1t, con1);
    k_gemm1<<<dim3(64, 4), 512, 0, stream>>>(x16, w1t, accbuf);
    k_ep<<<128, 256, 0, stream>>>(accbuf, con1, b1, r1, s2, s2q);
    k_w2t<<<128, 256, 0, stream>>>(W2, s2, s2q, bn2_g, bn2_b, w2t, con2);
    // accbuf dead; repurpose R as r2
    k_gemm2<<<dim3(8, 32), 512, 0, stream>>>(r1, w2t, con2, b2, r2, s3, s3q);
    k_final<<<B_SZ / 4, 256, 0, stream>>>(r2, s3, s3q, bn3_g, bn3_b, w3s, b3,
                                          lr_sc, (float*)d_out);
}

// Round 7
// 392.491 us; speedup vs baseline: 1.7537x; 1.0670x over previous
//
#include <hip/hip_runtime.h>

// ---------------- common helpers ----------------
typedef __attribute__((ext_vector_type(8))) short short8;
typedef __attribute__((ext_vector_type(4))) float f32x4;

__device__ __forceinline__ unsigned short f2b(float f) {
    union { float f; unsigned u; } uf; uf.f = f;
    unsigned r = uf.u + 0x7fffu + ((uf.u >> 16) & 1u);   // RNE, finite inputs
    return (unsigned short)(r >> 16);
}
__device__ __forceinline__ float b2f(unsigned short b) {
    union { unsigned u; float f; } uf; uf.u = ((unsigned)b) << 16;
    return uf.f;
}
__device__ __forceinline__ void gload_lds16(const void* g, void* l) {
    __builtin_amdgcn_global_load_lds(
        (const __attribute__((address_space(1))) void*)g,
        (__attribute__((address_space(3))) void*)l,
        16, 0, 0);
}

#define B_SZ 4096
#define F_ST 20
#define F_DY 10
#define MLEN 50
#define E_SZ 16
#define F_ALL 30
#define NPAIR 435
#define DIN 6960
#define KP 7168            /* DIN zero-padded; 8 k-slices of 896 (14 BK=64 steps) */
#define H_SZ 512
#define BN_EPS 1e-5f

// ---------------- static embedding gather (float4 per thread) ----------------
__global__ __launch_bounds__(256) void k_stemb(
    const int* __restrict__ st_ids, const float* __restrict__ st_emb,
    float* __restrict__ all_emb)
{
    int idx = blockIdx.x * 256 + threadIdx.x;    // (b*F_ST+f)*4 + e4
    int e4 = idx & 3, bf = idx >> 2;
    int b = bf / F_ST, f = bf % F_ST;
    int id = st_ids[bf];
    f32x4 v = *(const f32x4*)(st_emb + (long)id * E_SZ + e4 * 4);
    *(f32x4*)(all_emb + ((long)b * F_ALL + f) * E_SZ + e4 * 4) = v;
}

// ------- dynamic masked-mean: one wave per (b,f); ids broadcast via shfl -----
// Fully unrolled (13 fixed iterations): ~13 independent predicated loads in
// flight per lane. Every __shfl executes with ALL lanes active.
__global__ __launch_bounds__(512) void k_dyemb(
    const int* __restrict__ dy_ids, const int* __restrict__ dy_len,
    const float* __restrict__ dy_emb, float* __restrict__ all_emb)
{
    int gw = blockIdx.x * 8 + (threadIdx.x >> 6);   // wave id = b*F_DY + f
    int l = threadIdx.x & 63;
    int b = gw / F_DY, f = gw - b * F_DY;
    int len = dy_len[b * F_DY + f]; if (len < 1) len = 1;   // wave-uniform
    const int* ids = dy_ids + ((long)b * F_DY + f) * MLEN;
    int idv = (l < MLEN) ? ids[l] : 0;              // coalesced, one load/lane
    int e = l & 15, mq = l >> 4;
    float acc = 0.f;
#pragma unroll
    for (int j = 0; j < 13; ++j) {                  // 13*4 >= MLEN
        int m = mq + (j << 2);                      // m <= 51 < 64
        int id = __shfl(idv, m, 64);                // all 64 lanes active
        float v = (m < len) ? dy_emb[(long)id * E_SZ + e] : 0.f;
        acc += v;
    }
    acc += __shfl_xor(acc, 16, 64);
    acc += __shfl_xor(acc, 32, 64);
    if (l < 16)
        all_emb[((long)b * F_ALL + F_ST + f) * E_SZ + e] = acc / (float)len;
}

// ---------------- linear (lr) terms: one wave per batch row ----------------
__global__ __launch_bounds__(512) void k_lr(
    const int* __restrict__ st_ids, const int* __restrict__ dy_ids,
    const int* __restrict__ dy_len, const float* __restrict__ st_lr,
    const float* __restrict__ dy_lr, const float* __restrict__ bias,
    float* __restrict__ lr_score)
{
    int w = threadIdx.x >> 6, l = threadIdx.x & 63;
    int b = blockIdx.x * 8 + w;
    float acc = 0.f;
    if (l < F_ST) acc += st_lr[st_ids[b * F_ST + l]];
#pragma unroll
    for (int i = 0; i < 8; ++i) {                   // 10 fields x 50 slots = 500
        int idx = i * 64 + l;
        if (idx < F_DY * MLEN) {
            int f = idx / MLEN, m = idx - f * MLEN;
            int len = dy_len[b * F_DY + f]; if (len < 1) len = 1;
            if (m < len)
                acc += dy_lr[dy_ids[((long)b * F_DY + f) * MLEN + m]];
        }
    }
    for (int s = 32; s; s >>= 1) acc += __shfl_down(acc, s, 64);
    if (l == 0) lr_score[b] = bias[0] + acc;
}

// ---------- k_x: pairwise products -> x (bf16, K-padded) + BN1 stats --------
__global__ __launch_bounds__(256) void k_x(
    const float* __restrict__ all_emb, unsigned short* __restrict__ x16,
    float* __restrict__ s1, float* __restrict__ s1q)
{
    __shared__ float es[16 * 480];
    __shared__ int pip[NPAIR], pjp[NPAIR];
    int t = threadIdx.x, b0 = blockIdx.x * 16;
    for (int p = t; p < NPAIR; p += 256) {
        int i = 0, rem = p;
        while (rem >= (F_ALL - 1) - i) { rem -= (F_ALL - 1) - i; ++i; }
        pip[p] = i; pjp[p] = i + 1 + rem;
    }
    for (int idx = t; idx < 16 * 480; idx += 256)
        es[idx] = all_emb[(long)b0 * 480 + idx];
    __syncthreads();

    int ci[28], cj[28];
#pragma unroll
    for (int k = 0; k < 28; ++k) {
        int d = t + (k << 8);
        if (d < DIN) {
            int p = d >> 4, e = d & 15;
            ci[k] = pip[p] * E_SZ + e;
            cj[k] = pjp[p] * E_SZ + e;
        } else { ci[k] = -1; cj[k] = 0; }
    }
    float sum[28], sq[28];
#pragma unroll
    for (int k = 0; k < 28; ++k) { sum[k] = 0.f; sq[k] = 0.f; }

    for (int r = 0; r < 16; ++r) {
        const float* row = &es[r * 480];
        long ob = (long)(b0 + r) * KP;
#pragma unroll
        for (int k = 0; k < 28; ++k) {
            int d = t + (k << 8);
            if (ci[k] >= 0) {
                float v = row[ci[k]] * row[cj[k]];
                unsigned short h = f2b(v);
                x16[ob + d] = h;
                float vb = b2f(h);
                sum[k] += vb; sq[k] += vb * vb;
            } else {
                x16[ob + d] = 0;           // K padding
            }
        }
    }
#pragma unroll
    for (int k = 0; k < 28; ++k) {
        int d = t + (k << 8);
        if (ci[k] >= 0) { atomicAdd(&s1[d], sum[k]); atomicAdd(&s1q[d], sq[k]); }
    }
}

// ============ k_prep: BN1 fold (blocks 0..27) + W3 row-sums (28..59) ========
__global__ __launch_bounds__(256) void k_prep(
    const float* __restrict__ s, const float* __restrict__ sqs,
    const float* __restrict__ g, const float* __restrict__ bb,
    float* __restrict__ a, float* __restrict__ c,
    const float* __restrict__ W3, float* __restrict__ w3s)
{
    int t = threadIdx.x;
    if (blockIdx.x < 28) {
        int d = blockIdx.x * 256 + t;
        if (d < DIN) {
            float m = s[d] * (1.f / 4096.f);
            float var = sqs[d] * (1.f / 4096.f) - m * m;
            float av = g[d] * rsqrtf(var + BN_EPS);
            a[d] = av; c[d] = bb[d] - m * av;
        }
    } else {
        int row = (blockIdx.x - 28) * 16 + (t >> 4), sub = t & 15;
        float acc = 0.f;
        for (int i = 0; i < 32; ++i) acc += W3[(long)row * H_SZ + sub + i * 16];
#pragma unroll
        for (int sh = 8; sh; sh >>= 1) acc += __shfl_xor(acc, sh, 16);
        if (sub == 0) w3s[row] = acc;
    }
}

// ---------------- W1^T cast + const1 fold (w1t[n][k] = a1[k]*W1[k][n]) --------
__global__ __launch_bounds__(256) void k_w1t(
    const float* __restrict__ W1, const float* __restrict__ a1,
    const float* __restrict__ c1, unsigned short* __restrict__ w1t,
    float* __restrict__ con)
{
    int gi = blockIdx.x * 256 + threadIdx.x;   // 896*512 groups
    int kg = gi >> 9, n = gi & 511;
    short8 out; float cacc = 0.f;
#pragma unroll
    for (int i = 0; i < 8; ++i) {
        int k = kg * 8 + i;
        if (k < DIN) {
            float w = W1[(long)k * H_SZ + n];
            out[i] = (short)f2b(a1[k] * w);
            cacc += c1[k] * w;
        } else out[i] = 0;
    }
    *(short8*)(w1t + (long)n * KP + kg * 8) = out;
    atomicAdd(&con[n], cacc);
}

// ======== k_gemm1: output-stationary split-K bf16 MFMA, swizzled LDS ========
// tile M=64 x N=512; grid (64 m, 8 z) = 512 blocks (2/CU); BK=64, 14 steps.
// LDS rows are 128B; source chunk per lane is XOR-permuted (slot ^ row&7) so
// fragment reads hit 8 distinct bank groups (2-way only, free).
__global__ __launch_bounds__(512, 2) void k_gemm1(
    const unsigned short* __restrict__ A, const unsigned short* __restrict__ Bt,
    float* __restrict__ accbuf)
{
    __shared__ __align__(16) short As[64 * 64];    // 8 KB
    __shared__ __align__(16) short Bs[512 * 64];   // 64 KB
    const int t = threadIdx.x;
    const int w = t >> 6, l = t & 63;
    const int lm = l & 15, lq = l >> 4;
    const int row0 = blockIdx.x * 64;
    const int k0 = blockIdx.y * (KP / 8);          // 896-wide K slice

    const int srow = t >> 3;                       // staging row (0..63)
    const int gch = (t & 7) ^ (srow & 7);          // xor-permuted source chunk
    const unsigned short* gA = A + (long)(row0 + srow) * KP + k0 + gch * 8;
    const unsigned short* gB = Bt + (long)srow * KP + k0 + gch * 8;
    short* AsW = As + w * 512;                     // wave-contiguous dest
    short* BsW = Bs + w * 512;

    f32x4 acc[4][4];
#pragma unroll
    for (int mi = 0; mi < 4; ++mi)
#pragma unroll
        for (int ni = 0; ni < 4; ++ni) acc[mi][ni] = (f32x4){0.f,0.f,0.f,0.f};

    for (int kt = 0; kt < 14; ++kt) {
        gload_lds16(gA, AsW);                       // A: 64 rows x 64 k
#pragma unroll
        for (int c = 0; c < 8; ++c)                 // B: 512 rows x 64 k
            gload_lds16(gB + (long)(64 * c) * KP, BsW + c * 4096);
        __syncthreads();
#pragma unroll
        for (int s = 0; s < 2; ++s) {               // two 32-wide k sub-blocks
            short8 af[4];
#pragma unroll
            for (int mi = 0; mi < 4; ++mi) {
                int m = mi * 16 + lm;
                int sl = (s * 4 + lq) ^ (m & 7);
                af[mi] = *(const short8*)(As + m * 64 + sl * 8);
            }
#pragma unroll
            for (int ni = 0; ni < 4; ++ni) {
                int rb = w * 64 + ni * 16 + lm;
                int sl = (s * 4 + lq) ^ (rb & 7);
                short8 bf = *(const short8*)(Bs + rb * 64 + sl * 8);
#pragma unroll
                for (int mi = 0; mi < 4; ++mi)
                    acc[mi][ni] = __builtin_amdgcn_mfma_f32_16x16x32_bf16(
                        af[mi], bf, acc[mi][ni], 0, 0, 0);
            }
        }
        __syncthreads();
        gA += 64; gB += 64;
    }

    // C/D layout: col = lane&15 (n), row = (lane>>4)*4 + reg (m)
#pragma unroll
    for (int ni = 0; ni < 4; ++ni) {
        int col = w * 64 + ni * 16 + lm;
#pragma unroll
        for (int mi = 0; mi < 4; ++mi) {
            int rbase = row0 + mi * 16 + lq * 4;
#pragma unroll
            for (int r = 0; r < 4; ++r)
                atomicAdd(&accbuf[(long)(rbase + r) * H_SZ + col], acc[mi][ni][r]);
        }
    }
}

// ============ k_ep: accbuf -> relu(.+con1+b1) bf16 r1, + BN2 stats ==========
__global__ __launch_bounds__(256) void k_ep(
    const float* __restrict__ accbuf, const float* __restrict__ con1,
    const float* __restrict__ b1, unsigned short* __restrict__ r1,
    float* __restrict__ s2, float* __restrict__ s2q)
{
    __shared__ float con[H_SZ];
    int t = threadIdx.x, r0 = blockIdx.x * 32;
    con[t] = b1[t] + con1[t];
    con[t + 256] = b1[t + 256] + con1[t + 256];
    __syncthreads();
    float a0 = 0.f, q0 = 0.f, a1v = 0.f, q1 = 0.f;
    for (int r = 0; r < 32; ++r) {
        long base = (long)(r0 + r) * H_SZ;
        float v0 = accbuf[base + t] + con[t];
        float v1 = accbuf[base + t + 256] + con[t + 256];
        v0 = v0 > 0.f ? v0 : 0.f;
        v1 = v1 > 0.f ? v1 : 0.f;
        unsigned short h0 = f2b(v0), h1 = f2b(v1);
        r1[base + t] = h0; r1[base + t + 256] = h1;
        float b0 = b2f(h0), b1f = b2f(h1);
        a0 += b0; q0 += b0 * b0; a1v += b1f; q1 += b1f * b1f;
    }
    atomicAdd(&s2[t], a0);        atomicAdd(&s2q[t], q0);
    atomicAdd(&s2[t + 256], a1v); atomicAdd(&s2q[t + 256], q1);
}

// ============ k_w2t: inline BN2 fold + W2^T bf16 cast + con2 ================
__global__ __launch_bounds__(256) void k_w2t(
    const float* __restrict__ W2, const float* __restrict__ s2,
    const float* __restrict__ s2q, const float* __restrict__ g2,
    const float* __restrict__ bb2, unsigned short* __restrict__ w2t,
    float* __restrict__ con)
{
    int gi = blockIdx.x * 256 + threadIdx.x;   // 64 kg * 512 n
    int kg = gi >> 9, n = gi & 511;
    short8 out; float cacc = 0.f;
#pragma unroll
    for (int i = 0; i < 8; ++i) {
        int k = kg * 8 + i;
        float m = s2[k] * (1.f / 4096.f);
        float var = s2q[k] * (1.f / 4096.f) - m * m;
        float av = g2[k] * rsqrtf(var + BN_EPS);
        float cv = bb2[k] - m * av;
        float w = W2[(long)k * H_SZ + n];
        out[i] = (short)f2b(av * w);
        cacc += cv * w;
    }
    *(short8*)(w2t + (long)n * H_SZ + kg * 8) = out;
    atomicAdd(&con[n], cacc);
}

// ============ k_gemm2: full-K bf16 MFMA + fused relu + col stats ============
__global__ __launch_bounds__(512) void k_gemm2(
    const unsigned short* __restrict__ A, const unsigned short* __restrict__ Bt,
    const float* __restrict__ cvec, const float* __restrict__ bvec,
    unsigned short* __restrict__ Out, float* __restrict__ ss,
    float* __restrict__ sq)
{
    const int Kp = H_SZ;
    __shared__ __align__(16) short As[128 * 32];
    __shared__ __align__(16) short Bs[64 * 32];
    const int t = threadIdx.x;
    const int w = t >> 6, l = t & 63;
    const int wm = w >> 1, wn = w & 1;
    const int lm = l & 15, lq = l >> 4;
    const int row0 = blockIdx.y * 128;
    const int col0 = blockIdx.x * 64;

    const unsigned short* gA = A + (long)(row0 + (t >> 2)) * Kp + ((t & 3) * 8);
    const unsigned short* gB = Bt + (long)(col0 + ((t >> 2) & 63)) * Kp + ((t & 3) * 8);
    short* AsW = As + w * 512;
    short* BsW = Bs + w * 512;

    const short* aBase0 = As + (wm * 32 + lm) * 32 + lq * 8;
    const short* aBase1 = aBase0 + 16 * 32;
    const short* bBase0 = Bs + (wn * 32 + lm) * 32 + lq * 8;
    const short* bBase1 = bBase0 + 16 * 32;

    f32x4 acc00 = {0.f,0.f,0.f,0.f}, acc01 = acc00, acc10 = acc00, acc11 = acc00;

    for (int kt = 0; kt < Kp / 32; ++kt) {
        gload_lds16(gA, AsW);
        if (t < 256) gload_lds16(gB, BsW);
        __syncthreads();
        short8 af0 = *(const short8*)aBase0;
        short8 af1 = *(const short8*)aBase1;
        short8 bf0 = *(const short8*)bBase0;
        short8 bf1 = *(const short8*)bBase1;
        acc00 = __builtin_amdgcn_mfma_f32_16x16x32_bf16(af0, bf0, acc00, 0, 0, 0);
        acc01 = __builtin_amdgcn_mfma_f32_16x16x32_bf16(af0, bf1, acc01, 0, 0, 0);
        acc10 = __builtin_amdgcn_mfma_f32_16x16x32_bf16(af1, bf0, acc10, 0, 0, 0);
        acc11 = __builtin_amdgcn_mfma_f32_16x16x32_bf16(af1, bf1, acc11, 0, 0, 0);
        __syncthreads();
        gA += 32; gB += 32;
    }

    f32x4 accs[2][2] = {{acc00, acc01}, {acc10, acc11}};
#pragma unroll
    for (int ni = 0; ni < 2; ++ni) {
        int col = col0 + wn * 32 + ni * 16 + lm;
        float cb = cvec[col] + bvec[col];
        float psum = 0.f, psq = 0.f;
#pragma unroll
        for (int mi = 0; mi < 2; ++mi) {
            int rbase = row0 + wm * 32 + mi * 16 + lq * 4;
#pragma unroll
            for (int r = 0; r < 4; ++r) {
                float v = accs[mi][ni][r] + cb;
                v = v > 0.f ? v : 0.f;
                unsigned short h = f2b(v);
                Out[(long)(rbase + r) * H_SZ + col] = h;
                float vb = b2f(h);
                psum += vb; psq += vb * vb;
            }
        }
        psum += __shfl_xor(psum, 16, 64); psum += __shfl_xor(psum, 32, 64);
        psq  += __shfl_xor(psq , 16, 64); psq  += __shfl_xor(psq , 32, 64);
        if (lq == 0) { atomicAdd(&ss[col], psum); atomicAdd(&sq[col], psq); }
    }
}

// ============ k_final: inline BN3 fold + GEMV + lr ==========================
__global__ __launch_bounds__(256) void k_final(
    const unsigned short* __restrict__ r2, const float* __restrict__ s3,
    const float* __restrict__ s3q, const float* __restrict__ g3,
    const float* __restrict__ bb3, const float* __restrict__ w3s,
    const float* __restrict__ b3, const float* __restrict__ lr_score,
    float* __restrict__ out)
{
    int t = threadIdx.x, w = t >> 6, l = t & 63;
    int b = blockIdx.x * 4 + w;
    float acc = 0.f;
#pragma unroll
    for (int i = 0; i < 8; ++i) {
        int e = i * 64 + l;
        float m = s3[e] * (1.f / 4096.f);
        float var = s3q[e] * (1.f / 4096.f) - m * m;
        float a3 = g3[e] * rsqrtf(var + BN_EPS);
        float c3 = bb3[e] - m * a3;
        float v = a3 * b2f(r2[(long)b * H_SZ + e]) + c3;
        acc += v * w3s[e] + b3[e];
    }
    for (int s = 32; s; s >>= 1) acc += __shfl_down(acc, s, 64);
    if (l == 0) out[b] = lr_score[b] + acc;
}

// ---------------- launcher ----------------
extern "C" void kernel_launch(void* const* d_in, const int* in_sizes, int n_in,
                              void* d_out, int out_size, void* d_ws, size_t ws_size,
                              hipStream_t stream) {
    const int*   st_ids = (const int*)d_in[0];
    const int*   dy_ids = (const int*)d_in[1];
    const int*   dy_len = (const int*)d_in[2];
    const float* st_emb = (const float*)d_in[3];
    const float* dy_emb = (const float*)d_in[4];
    const float* st_lr  = (const float*)d_in[5];
    const float* dy_lr  = (const float*)d_in[6];
    const float* bias   = (const float*)d_in[7];
    const float* bn1_g  = (const float*)d_in[8];
    const float* bn1_b  = (const float*)d_in[9];
    const float* W1     = (const float*)d_in[10];
    const float* b1     = (const float*)d_in[11];
    const float* bn2_g  = (const float*)d_in[12];
    const float* bn2_b  = (const float*)d_in[13];
    const float* W2     = (const float*)d_in[14];
    const float* b2     = (const float*)d_in[15];
    const float* bn3_g  = (const float*)d_in[16];
    const float* bn3_b  = (const float*)d_in[17];
    const float* W3     = (const float*)d_in[18];
    const float* b3     = (const float*)d_in[19];
    // d_in[20..23] feed only the dead final layer — skipped.

    char* ws = (char*)d_ws;
    size_t off = 0;
    auto alloc = [&](size_t bytes) -> char* {
        char* p = ws + off;
        off = (off + bytes + 255) & ~(size_t)255;
        return p;
    };
    // Union region R (8.39 MB), time-multiplexed:
    //   phase 1: all_emb (7.87 MB)   [k_stemb..k_x]
    //   phase 2: accbuf  (8.39 MB)   [memset -> k_gemm1 -> k_ep]
    //   phase 3: r2      (4.19 MB)   [k_gemm2 -> k_final]
    char* R = alloc((size_t)B_SZ * H_SZ * 4);      // 8,388,608 B
    float*          all_emb = (float*)R;
    float*          accbuf  = (float*)R;
    unsigned short* r2      = (unsigned short*)R;

    unsigned short* x16     = (unsigned short*)alloc((size_t)B_SZ * KP * 2);
    unsigned short* w1t     = (unsigned short*)alloc((size_t)H_SZ * KP * 2);
    unsigned short* r1      = (unsigned short*)alloc((size_t)B_SZ * H_SZ * 2);
    unsigned short* w2t     = (unsigned short*)alloc((size_t)H_SZ * H_SZ * 2);
    float*          lr_sc   = (float*)alloc(B_SZ * 4);
    float* a1  = (float*)alloc(KP * 4);
    float* c1  = (float*)alloc(KP * 4);
    float* w3s = (float*)alloc(H_SZ * 4);
    char* zstart = ws + off;                       // ---- zeroed stats ----
    float* s1   = (float*)alloc(KP * 4);
    float* s1q  = (float*)alloc(KP * 4);
    float* con1 = (float*)alloc(H_SZ * 4);
    float* s2   = (float*)alloc(H_SZ * 4);
    float* s2q  = (float*)alloc(H_SZ * 4);
    float* con2 = (float*)alloc(H_SZ * 4);
    float* s3   = (float*)alloc(H_SZ * 4);
    float* s3q  = (float*)alloc(H_SZ * 4);
    size_t zbytes = (size_t)((ws + off) - zstart);
    // total ws use ≈ 79.3 MB (< 81.2 MB proven safe)

    hipMemsetAsync(zstart, 0, zbytes, stream);
    k_stemb<<<(B_SZ * F_ST * 4) / 256, 256, 0, stream>>>(st_ids, st_emb, all_emb);
    k_dyemb<<<(B_SZ * F_DY) / 8, 512, 0, stream>>>(dy_ids, dy_len, dy_emb, all_emb);
    k_lr<<<B_SZ / 8, 512, 0, stream>>>(st_ids, dy_ids, dy_len, st_lr, dy_lr,
                                       bias, lr_sc);
    k_x<<<B_SZ / 16, 256, 0, stream>>>(all_emb, x16, s1, s1q);
    // all_emb dead; repurpose R as zeroed fp32 accumulator
    hipMemsetAsync(R, 0, (size_t)B_SZ * H_SZ * 4, stream);
    k_prep<<<60, 256, 0, stream>>>(s1, s1q, bn1_g, bn1_b, a1, c1, W3, w3s);
    k_w1t<<<(896 * 512) / 256, 256, 0, stream>>>(W1, a1, c1, w1t, con1);
    k_gemm1<<<dim3(64, 8), 512, 0, stream>>>(x16, w1t, accbuf);
    k_ep<<<128, 256, 0, stream>>>(accbuf, con1, b1, r1, s2, s2q);
    k_w2t<<<128, 256, 0, stream>>>(W2, s2, s2q, bn2_g, bn2_b, w2t, con2);
    // accbuf dead; repurpose R as r2
    k_gemm2<<<dim3(8, 32), 512, 0, stream>>>(r1, w2t, con2, b2, r2, s3, s3q);
    k_final<<<B_SZ / 4, 256, 0, stream>>>(r2, s3, s3q, bn3_g, bn3_b, w3s, b3,
                                          lr_sc, (float*)d_out);
}